// Round 16
// baseline (321.858 us; speedup 1.0000x reference)
//
#include <hip/hip_runtime.h>
#include <math.h>

typedef __attribute__((ext_vector_type(8))) short bf16x8;
typedef __attribute__((ext_vector_type(4))) float f32x4;
typedef unsigned short u16;
typedef unsigned int u32;

#define DEVFN static __device__ __forceinline__

constexpr int NB  = 32;
constexpr int DLn = 290;
constexpr int PLc = 1000;
constexpr int MD  = NB * DLn;   // 9280  = 145*64
constexpr int MP  = NB * PLc;   // 32000 = 500*64
constexpr int NSTRIP = 645;     // 64-row strips: 145 drug + 500 prot
constexpr int SPLIT  = 145;
constexpr int SG     = 81;      // ceil(645/8)

DEVFN u16 f2b(float f) {
    u32 u = __builtin_bit_cast(u32, f);
    u32 r = u + 0x7fffu + ((u >> 16) & 1u);
    return (u16)(r >> 16);
}
DEVFN float b2f(u16 s) { return __builtin_bit_cast(float, (u32)s << 16); }
DEVFN float sigm(float x) { return 1.0f / (1.0f + __expf(-x)); }
// XOR-swizzled LDS index (u16 units); stride multiple of 8 u16. 16B-aligned.
DEVFN int sw(int row, int col, int stride) { return row * stride + (col ^ ((row & 7) << 3)); }

// ---------------- PE table ----------------
__global__ void pe_kernel(float* __restrict__ pe) {
    int p = blockIdx.x, c = threadIdx.x;
    float div = __expf((float)(c & ~1) * (-9.210340371976184f / 256.0f));
    float ang = (float)p * div;
    pe[p * 256 + c] = (c & 1) ? cosf(ang) : sinf(ang);
}

// ---------------- drug fc precompute ----------------
__global__ void fcprep_kernel(const float* __restrict__ w, const float* __restrict__ b,
                              float* __restrict__ dfc) {
    int c = threadIdx.x;
    float s = b[c];
    #pragma unroll
    for (int hh = 0; hh < 8; hh++) s += 0.001f * w[hh * 256 + c];
    dfc[c] = s;
}

// ---------------- weight prep: WT[n][k] bf16, LDS transpose ----------------
struct WPtrs { const float* w[10]; };
__global__ __launch_bounds__(256) void wprep_kernel(WPtrs wp, u16* __restrict__ wt) {
    __shared__ u16 t[64][66];
    int m = blockIdx.y, tile = blockIdx.x;
    int k0 = (tile >> 2) * 64, n0 = (tile & 3) * 64;
    const float* w = wp.w[m];
    int r = threadIdx.x >> 6, c = threadIdx.x & 63;
    #pragma unroll
    for (int q = 0; q < 16; q++) {
        int rr = r + q * 4;
        t[rr][c] = f2b(w[(size_t)(k0 + rr) * 256 + n0 + c]);
    }
    __syncthreads();
    #pragma unroll
    for (int q = 0; q < 16; q++) {
        int rr = r + q * 4;
        wt[((size_t)m << 16) + (size_t)(n0 + rr) * 256 + k0 + c] = t[c][rr];
    }
}

// ---------------- projection: ONE 64x64 tile per block, single K=256 phase ----------------
// NM==4 (proj1): A fragments built on the fly from fp32 X + scale*pe (eadd fused).
// NM==1 (proj2): A from bf16 ctx; epilogue fuses the final combine.
struct PM { const u16* BT; const float* bias; u16* C; int sig; };
struct PCfg {
    const u16* Ab;
    PM m[4];
};
struct PCfg2 {
    PCfg c0, c1;
    const float* x0; const float* x1;
    const u16* gate0; const u16* gate1;
    const float* cm;
    const float* dfc;
    const float* wfc1; const float* bfc1;
    const float* scale0; const float* scale1;
    const float* pe;
    float* out;
};

template<int NM>
__global__ __launch_bounds__(256) void proj_kernel(PCfg2 cfgs) {
    const int d = blockIdx.x;
    const int x = d & 7, q = d >> 3;
    const int u  = (NM == 4) ? (q & 15) : (q & 3);
    const int sg = (NM == 4) ? (q >> 4) : (q >> 2);
    const int s = sg * 8 + x;
    if (s >= NSTRIP) return;
    const int mi = (NM == 4) ? (u >> 2) : 0;
    const int nt = (NM == 4) ? (u & 3) : u;
    const bool f1 = s < SPLIT;
    const int mt = f1 ? s : s - SPLIT;

    const u16* Ab   = f1 ? cfgs.c0.Ab : cfgs.c1.Ab;
    const u16*   BT   = f1 ? (mi==0?cfgs.c0.m[0].BT  :mi==1?cfgs.c0.m[1].BT  :mi==2?cfgs.c0.m[2].BT  :cfgs.c0.m[3].BT)
                           : (mi==0?cfgs.c1.m[0].BT  :mi==1?cfgs.c1.m[1].BT  :mi==2?cfgs.c1.m[2].BT  :cfgs.c1.m[3].BT);
    const float* bias = f1 ? (mi==0?cfgs.c0.m[0].bias:mi==1?cfgs.c0.m[1].bias:mi==2?cfgs.c0.m[2].bias:cfgs.c0.m[3].bias)
                           : (mi==0?cfgs.c1.m[0].bias:mi==1?cfgs.c1.m[1].bias:mi==2?cfgs.c1.m[2].bias:cfgs.c1.m[3].bias);
    u16*         C    = f1 ? (mi==0?cfgs.c0.m[0].C   :mi==1?cfgs.c0.m[1].C   :mi==2?cfgs.c0.m[2].C   :cfgs.c0.m[3].C)
                           : (mi==0?cfgs.c1.m[0].C   :mi==1?cfgs.c1.m[1].C   :mi==2?cfgs.c1.m[2].C   :cfgs.c1.m[3].C);
    const int    sig  = f1 ? (mi==0?cfgs.c0.m[0].sig :mi==1?cfgs.c0.m[1].sig :mi==2?cfgs.c0.m[2].sig :cfgs.c0.m[3].sig)
                           : (mi==0?cfgs.c1.m[0].sig :mi==1?cfgs.c1.m[1].sig :mi==2?cfgs.c1.m[2].sig :cfgs.c1.m[3].sig);

    __shared__ u16 Bs[64 * 256];                 // 32 KB
    __shared__ float fcb[(NM == 1) ? 2304 : 4];  // prot fc (9 KB, NM==1 only)
    const int tid = threadIdx.x;
    const int lane = tid & 63, w = tid >> 6, ln = lane & 15, g = lane >> 4;

    // ---- B tile load to regs (issued first; row permuted by nu) ----
    const int lr = tid >> 2, lc = tid & 3;
    const int nur = ((lr >> 5) & 1) * 32 + ((lr >> 2) & 3) * 8 + ((lr >> 4) & 1) * 4 + (lr & 3);
    const u16* Bp = BT + (size_t)(nt * 64 + nur) * 256 + lc * 8;
    uint4 bv[8];
    #pragma unroll
    for (int kk = 0; kk < 8; kk++) bv[kk] = *(const uint4*)(Bp + kk * 32);

    // ---- A fragments in registers: row mt*64 + w*16 + ln ----
    const int row = mt * 64 + w * 16 + ln;
    bf16x8 Af[8];
    if (NM == 4) {
        // fused eadd: e = x + scale*pe (fp32 in, bf16 fragments out)
        const float* X     = f1 ? cfgs.x0 : cfgs.x1;
        const float* scale = f1 ? cfgs.scale0 : cfgs.scale1;
        const int pos = f1 ? (row % DLn) : (row % PLc);
        const float sc = scale[0];
        const float* Xp_ = X + (size_t)row * 256 + g * 8;
        const float* Pe_ = cfgs.pe + (size_t)pos * 256 + g * 8;
        #pragma unroll
        for (int ks = 0; ks < 8; ks++) {
            float4 xa = *(const float4*)(Xp_ + ks * 32);
            float4 xb = *(const float4*)(Xp_ + ks * 32 + 4);
            float4 pa = *(const float4*)(Pe_ + ks * 32);
            float4 pb = *(const float4*)(Pe_ + ks * 32 + 4);
            u16 o[8];
            o[0] = f2b(xa.x + sc * pa.x); o[1] = f2b(xa.y + sc * pa.y);
            o[2] = f2b(xa.z + sc * pa.z); o[3] = f2b(xa.w + sc * pa.w);
            o[4] = f2b(xb.x + sc * pb.x); o[5] = f2b(xb.y + sc * pb.y);
            o[6] = f2b(xb.z + sc * pb.z); o[7] = f2b(xb.w + sc * pb.w);
            Af[ks] = *(bf16x8*)o;
        }
    } else {
        const u16* Ap = Ab + (size_t)row * 256 + g * 8;
        #pragma unroll
        for (int ks = 0; ks < 8; ks++)
            Af[ks] = *(const bf16x8*)(Ap + ks * 32);
    }

    if (NM == 1 && !f1) {
        *(float4*)&fcb[tid * 8]     = *(const float4*)&cfgs.wfc1[tid * 8];
        *(float4*)&fcb[tid * 8 + 4] = *(const float4*)&cfgs.wfc1[tid * 8 + 4];
        fcb[2048 + tid] = cfgs.bfc1[tid];
    }

    #pragma unroll
    for (int kk = 0; kk < 8; kk++)
        *(uint4*)&Bs[sw(lr, lc * 8 + kk * 32, 256)] = bv[kk];
    __syncthreads();

    // ---- compute: D = Bfrag * Afrag (C^T fragment) ----
    f32x4 acc[4] = {};
    #pragma unroll
    for (int ks = 0; ks < 8; ks++) {
        #pragma unroll
        for (int ntl = 0; ntl < 4; ntl++) {
            bf16x8 bf = *(const bf16x8*)&Bs[sw(ntl * 16 + ln, ks * 32 + g * 8, 256)];
            acc[ntl] = __builtin_amdgcn_mfma_f32_16x16x32_bf16(bf, Af[ks], acc[ntl], 0, 0, 0);
        }
    }

    // ---- epilogue: thread owns row, 16 consecutive cols (2 x 16B) ----
    const int base0 = nt * 64 + g * 8, base1 = base0 + 32;
    f32x4 b0 = *(const f32x4*)&bias[base0];
    f32x4 b1 = *(const f32x4*)&bias[base0 + 4];
    f32x4 b2 = *(const f32x4*)&bias[base1];
    f32x4 b3 = *(const f32x4*)&bias[base1 + 4];
    float v[16];
    #pragma unroll
    for (int t = 0; t < 4; t++) {
        v[t]      = acc[0][t] + b0[t];
        v[4 + t]  = acc[1][t] + b1[t];
        v[8 + t]  = acc[2][t] + b2[t];
        v[12 + t] = acc[3][t] + b3[t];
    }
    if (NM == 4) {
        if (sig) {
            #pragma unroll
            for (int t = 0; t < 16; t++) v[t] = sigm(v[t]);
        }
        u16 o[16];
        #pragma unroll
        for (int t = 0; t < 16; t++) o[t] = f2b(v[t]);
        u16* Cp = C + (size_t)row * 256;
        *(uint4*)&Cp[base0] = *(uint4*)&o[0];
        *(uint4*)&Cp[base1] = *(uint4*)&o[8];
    } else {
        // fused combine: out = e + v*gate*sigm(aw), fp32
        (void)C; (void)sig;
        const float* X     = f1 ? cfgs.x0 : cfgs.x1;
        const u16* gate    = f1 ? cfgs.gate0 : cfgs.gate1;
        const float* scale = f1 ? cfgs.scale0 : cfgs.scale1;
        const float* pe    = cfgs.pe;
        const float sc = scale[0];
        const int pos  = f1 ? (row % DLn) : (row % PLc);
        const int bidx = f1 ? (row / DLn) : (row / PLc);
        const int orow = bidx * 1290 + (f1 ? pos : 290 + pos);
        float aw[16];
        if (f1) {
            const float* dfc = cfgs.dfc;
            *(float4*)&aw[0]  = *(const float4*)&dfc[base0];
            *(float4*)&aw[4]  = *(const float4*)&dfc[base0 + 4];
            *(float4*)&aw[8]  = *(const float4*)&dfc[base1];
            *(float4*)&aw[12] = *(const float4*)&dfc[base1 + 4];
        } else {
            float cmv[8];
            float4 ca = *(const float4*)&cfgs.cm[(size_t)row * 8];
            float4 cb = *(const float4*)&cfgs.cm[(size_t)row * 8 + 4];
            cmv[0]=ca.x; cmv[1]=ca.y; cmv[2]=ca.z; cmv[3]=ca.w;
            cmv[4]=cb.x; cmv[5]=cb.y; cmv[6]=cb.z; cmv[7]=cb.w;
            #pragma unroll
            for (int t = 0; t < 16; t++) {
                const int col = (t < 8) ? (base0 + t) : (base1 + t - 8);
                float s2 = fcb[2048 + col];
                #pragma unroll
                for (int hh = 0; hh < 8; hh++) s2 += cmv[hh] * fcb[hh * 256 + col];
                aw[t] = s2;
            }
        }
        u16 ge[16];
        *(uint4*)&ge[0] = *(const uint4*)&gate[(size_t)row * 256 + base0];
        *(uint4*)&ge[8] = *(const uint4*)&gate[(size_t)row * 256 + base1];
        float outv[16];
        #pragma unroll
        for (int half = 0; half < 2; half++) {
            const int cb0 = half ? base1 : base0;
            #pragma unroll
            for (int t4 = 0; t4 < 2; t4++) {
                float4 xa = *(const float4*)&X[(size_t)row * 256 + cb0 + t4 * 4];
                float4 pa = *(const float4*)&pe[(size_t)pos * 256 + cb0 + t4 * 4];
                #pragma unroll
                for (int t = 0; t < 4; t++) {
                    const int idx = half * 8 + t4 * 4 + t;
                    float e = (&xa.x)[t] + sc * (&pa.x)[t];
                    outv[idx] = e + v[idx] * b2f(ge[idx]) * sigm(aw[idx]);
                }
            }
        }
        float* Op = cfgs.out + (size_t)orow * 256;
        *(float4*)&Op[base0]     = *(float4*)&outv[0];
        *(float4*)&Op[base0 + 4] = *(float4*)&outv[4];
        *(float4*)&Op[base1]     = *(float4*)&outv[8];
        *(float4*)&Op[base1 + 4] = *(float4*)&outv[12];
    }
}

// ---------------- attention: one block per (b,h), no-max softmax, 2 sweeps ----------------
// Q' scales folded with log2(e): S in log2 domain -> P = exp2(S) (bare v_exp_f32).
// P -> bf16 via scalar f2b (compiler-schedulable; inline-asm cvt_pk regressed, R14).
__global__ __launch_bounds__(512) void attn_kernel(
        const u16* __restrict__ Qd, const u16* __restrict__ Kd, const u16* __restrict__ Vd,
        const u16* __restrict__ Kp, const u16* __restrict__ Vp, const u16* __restrict__ Qp,
        const float* __restrict__ alpha,
        u16* __restrict__ ctx_d, u16* __restrict__ ctx_p, float* __restrict__ cm) {
    __shared__ u16 Ks[2][64 * 64];
    __shared__ union {
        struct { u16 VpT[2][32 * 64]; u16 Pm[320 * 64]; } s1;
        struct { u16 PT[64 * 320]; u16 VdT[32 * 320]; } s2;
    } U;
    __shared__ float r_l[320];
    __shared__ float colpart[8][64];

    const int bh = blockIdx.x, b = bh >> 3, h = bh & 7;
    const int tid = threadIdx.x;
    const int w = tid >> 6, lane = tid & 63, ln = lane & 15, g = lane >> 4;

    const float a = sigm(alpha[0]);
    const float inv = 0.1767766952966369f;       // 1/sqrt(32)
    const float l2e = 1.4426950408889634f;       // log2(e)
    const float sa = a * inv * l2e, sb = (1.0f - a) * inv * l2e;
    const int nmt = (w < 4) ? 3 : 2;
    const int mtsA[3] = { w, w + 8, w + 16 };

    const size_t rbd = (size_t)b * DLn * 256 + h * 32;
    const size_t rbp = (size_t)b * PLc * 256 + h * 32;

    bf16x8 Qf[3][2];
    #pragma unroll
    for (int t = 0; t < 3; t++) {
        const int i = mtsA[t] * 16 + ln;
        #pragma unroll
        for (int ks = 0; ks < 2; ks++) {
            u16 o[8] = {0,0,0,0,0,0,0,0};
            if (t < nmt && i < DLn) {
                const u16* src = (ks ? Kd : Qd) + rbd + (size_t)i * 256 + g * 8;
                const float s = ks ? sb : sa;
                uint4 v = *(const uint4*)src;
                u16 e[8]; *(uint4*)e = v;
                #pragma unroll
                for (int q = 0; q < 8; q++) o[q] = f2b(b2f(e[q]) * s);
            }
            Qf[t][ks] = *(bf16x8*)o;
        }
    }

    const int s_jj = tid >> 3, s_ch = tid & 7;
    const u16* s_src = ((s_ch >> 2) ? Qp : Kp) + rbp + (s_ch & 3) * 8;
    const int v_j = tid & 63, v_d0 = (tid >> 6) * 4;

    {
        int j = s_jj;
        uint4 kv = (j < PLc) ? *(const uint4*)(s_src + (size_t)j * 256) : make_uint4(0,0,0,0);
        uint2 vv = (v_j < PLc) ? *(const uint2*)(Vp + rbp + (size_t)v_j * 256 + v_d0) : make_uint2(0,0);
        *(uint4*)&Ks[0][sw(s_jj, s_ch * 8, 64)] = kv;
        u16 e[4]; *(uint2*)e = vv;
        #pragma unroll
        for (int q = 0; q < 4; q++) U.s1.VpT[0][sw(v_d0 + q, v_j, 64)] = e[q];
    }
    __syncthreads();

    float rs[3] = {0.f, 0.f, 0.f};
    f32x4 accd[3][2] = {};
    for (int jt = 0; jt < 16; jt++) {
        const int cur = jt & 1, j0 = jt * 64;
        const int jn = j0 + 64 + s_jj;
        uint4 kv = (jn < PLc) ? *(const uint4*)(s_src + (size_t)jn * 256) : make_uint4(0,0,0,0);
        const int vn = j0 + 64 + v_j;
        uint2 vv = (vn < PLc) ? *(const uint2*)(Vp + rbp + (size_t)vn * 256 + v_d0) : make_uint2(0,0);

        bf16x8 kf[4][2];
        #pragma unroll
        for (int js = 0; js < 4; js++)
            #pragma unroll
            for (int ks = 0; ks < 2; ks++)
                kf[js][ks] = *(const bf16x8*)&Ks[cur][sw(js * 16 + ln, ks * 32 + g * 8, 64)];

        #pragma unroll
        for (int t = 0; t < 3; t++) {
            if (t >= nmt) break;
            const int mt = mtsA[t];
            f32x4 acc[4] = {};
            #pragma unroll
            for (int ks = 0; ks < 2; ks++)
                #pragma unroll
                for (int js = 0; js < 4; js++)
                    acc[js] = __builtin_amdgcn_mfma_f32_16x16x32_bf16(kf[js][ks], Qf[t][ks], acc[js], 0, 0, 0);
            const int irow = mt * 16 + ln;
            #pragma unroll
            for (int js = 0; js < 4; js++) {
                u16 pb[4];
                float psum = 0.f;
                #pragma unroll
                for (int r = 0; r < 4; r++) {
                    float p = exp2f(acc[js][r]);
                    psum += p;
                    pb[r] = f2b(p);
                }
                rs[t] += psum;
                *(ushort4*)&U.s1.Pm[sw(irow, js * 16 + g * 4, 64)] = *(ushort4*)pb;
            }
        }
        #pragma unroll
        for (int t = 0; t < 3; t++) {
            if (t >= nmt) break;
            const int mt = mtsA[t];
            #pragma unroll
            for (int ks2 = 0; ks2 < 2; ks2++) {
                bf16x8 af = *(const bf16x8*)&U.s1.Pm[sw(mt * 16 + ln, ks2 * 32 + g * 8, 64)];
                #pragma unroll
                for (int nd = 0; nd < 2; nd++) {
                    bf16x8 bv = *(const bf16x8*)&U.s1.VpT[cur][sw(nd * 16 + ln, ks2 * 32 + g * 8, 64)];
                    accd[t][nd] = __builtin_amdgcn_mfma_f32_16x16x32_bf16(bv, af, accd[t][nd], 0, 0, 0);
                }
            }
        }
        *(uint4*)&Ks[cur ^ 1][sw(s_jj, s_ch * 8, 64)] = kv;
        {
            u16 e[4]; *(uint2*)e = vv;
            #pragma unroll
            for (int q = 0; q < 4; q++) U.s1.VpT[cur ^ 1][sw(v_d0 + q, v_j, 64)] = e[q];
        }
        __syncthreads();
    }

    #pragma unroll
    for (int t = 0; t < 3; t++) {
        float v = rs[t];
        v += __shfl_xor(v, 16);
        v += __shfl_xor(v, 32);
        rs[t] = v;
    }
    if (g == 0) {
        #pragma unroll
        for (int t = 0; t < 3; t++) {
            if (t >= nmt) break;
            const int i = mtsA[t] * 16 + ln;
            r_l[i] = (i < DLn) ? 1.0f / (rs[t] - 24.0f) : 0.0f;
        }
    }
    __syncthreads();

    #pragma unroll
    for (int t = 0; t < 3; t++) {
        if (t >= nmt) break;
        const int i = mtsA[t] * 16 + ln;
        if (i < DLn) {
            const float ri = r_l[i];
            #pragma unroll
            for (int nd = 0; nd < 2; nd++) {
                u16 o[4];
                #pragma unroll
                for (int r = 0; r < 4; r++) o[r] = f2b(accd[t][nd][r] * ri);
                *(uint2*)&ctx_d[rbd + (size_t)i * 256 + nd * 16 + g * 4] = *(uint2*)o;
            }
        }
    }
    for (int c = tid; c < 320 * 8; c += 512) {
        const int i = c >> 3, d0 = (c & 7) * 4;
        u16 o[4] = {0,0,0,0};
        if (i < DLn) {
            const float ri = r_l[i];
            uint2 v = *(const uint2*)(Vd + rbd + (size_t)i * 256 + d0);
            u16 e[4]; *(uint2*)e = v;
            #pragma unroll
            for (int q = 0; q < 4; q++) o[q] = f2b(b2f(e[q]) * ri);
        }
        #pragma unroll
        for (int q = 0; q < 4; q++) U.s2.VdT[sw(d0 + q, i, 320)] = o[q];
    }
    {
        int j = s_jj;
        uint4 kv = (j < PLc) ? *(const uint4*)(s_src + (size_t)j * 256) : make_uint4(0,0,0,0);
        *(uint4*)&Ks[0][sw(s_jj, s_ch * 8, 64)] = kv;
    }
    float rr[3][4];
    #pragma unroll
    for (int t = 0; t < 3; t++)
        #pragma unroll
        for (int r = 0; r < 4; r++)
            rr[t][r] = (t < nmt) ? r_l[mtsA[t] * 16 + g * 4 + r] : 0.0f;
    __syncthreads();

    for (int jt = 0; jt < 16; jt++) {
        const int cur = jt & 1, j0 = jt * 64;
        const int jn = j0 + 64 + s_jj;
        uint4 kv = (jn < PLc) ? *(const uint4*)(s_src + (size_t)jn * 256) : make_uint4(0,0,0,0);

        bf16x8 kf[4][2];
        #pragma unroll
        for (int js = 0; js < 4; js++)
            #pragma unroll
            for (int ks = 0; ks < 2; ks++)
                kf[js][ks] = *(const bf16x8*)&Ks[cur][sw(js * 16 + ln, ks * 32 + g * 8, 64)];

        float csl[4] = {0.f, 0.f, 0.f, 0.f};
        #pragma unroll
        for (int t = 0; t < 3; t++) {
            if (t >= nmt) break;
            const int mt = mtsA[t];
            f32x4 acc[4] = {};
            #pragma unroll
            for (int ks = 0; ks < 2; ks++)
                #pragma unroll
                for (int js = 0; js < 4; js++)
                    acc[js] = __builtin_amdgcn_mfma_f32_16x16x32_bf16(Qf[t][ks], kf[js][ks], acc[js], 0, 0, 0);
            #pragma unroll
            for (int js = 0; js < 4; js++) {
                u16 pb[4];
                #pragma unroll
                for (int r = 0; r < 4; r++) {
                    float p = exp2f(acc[js][r]);
                    csl[js] += p * rr[t][r];
                    pb[r] = f2b(p);
                }
                *(ushort4*)&U.s2.PT[sw(js * 16 + ln, mt * 16 + g * 4, 320)] = *(ushort4*)pb;
            }
        }
        #pragma unroll
        for (int js = 0; js < 4; js++) {
            float v = csl[js];
            v += __shfl_xor(v, 16);
            v += __shfl_xor(v, 32);
            csl[js] = v;
        }
        if (g == 0) {
            #pragma unroll
            for (int js = 0; js < 4; js++) colpart[w][js * 16 + ln] = csl[js];
        }
        *(uint4*)&Ks[cur ^ 1][sw(s_jj, s_ch * 8, 64)] = kv;
        __syncthreads();

        {
            const int js2 = w & 3, ds2 = w >> 2;
            f32x4 ap = {};
            #pragma unroll
            for (int k = 0; k < 10; k++) {
                bf16x8 af = *(const bf16x8*)&U.s2.PT[sw(js2 * 16 + ln, k * 32 + g * 8, 320)];
                bf16x8 bv = *(const bf16x8*)&U.s2.VdT[sw(ds2 * 16 + ln, k * 32 + g * 8, 320)];
                ap = __builtin_amdgcn_mfma_f32_16x16x32_bf16(bv, af, ap, 0, 0, 0);
            }
            const int j = j0 + js2 * 16 + ln;
            if (j < PLc) {
                u16 o[4];
                #pragma unroll
                for (int r = 0; r < 4; r++) o[r] = f2b(ap[r]);
                *(uint2*)&ctx_p[rbp + (size_t)j * 256 + ds2 * 16 + g * 4] = *(uint2*)o;
            }
        }
        if (w == 0) {
            float tot = 0.f;
            #pragma unroll
            for (int ww = 0; ww < 8; ww++) tot += colpart[ww][lane];
            const int j = j0 + lane;
            if (j < PLc) cm[(size_t)(b * PLc + j) * 8 + h] = tot * (1.0f / 290.0f);
        }
        __syncthreads();
    }
}

extern "C" void kernel_launch(void* const* d_in, const int* in_sizes, int n_in,
                              void* d_out, int out_size, void* d_ws, size_t ws_size,
                              hipStream_t stream) {
    (void)in_sizes; (void)n_in; (void)out_size;
    const float* drug    = (const float*)d_in[0];
    const float* prot    = (const float*)d_in[1];
    const float* scale_d = (const float*)d_in[2];
    const float* scale_p = (const float*)d_in[3];

    char* ws = (char*)d_ws;
    size_t off = 0;
    auto alloc = [&](size_t bytes) -> void* {
        void* p = ws + off;
        off += (bytes + 255) & ~(size_t)255;
        return p;
    };
    float* pe   = (float*)alloc((size_t)1000 * 256 * 4);
    u16* wt     = (u16*)alloc((size_t)10 * 65536 * 2);
    u16* Qd     = (u16*)alloc((size_t)MD * 256 * 2);
    u16* Kd     = (u16*)alloc((size_t)MD * 256 * 2);
    u16* Vd     = (u16*)alloc((size_t)MD * 256 * 2);
    u16* gate_d = (u16*)alloc((size_t)MD * 256 * 2);
    u16* Kp     = (u16*)alloc((size_t)MP * 256 * 2);
    u16* Vp     = (u16*)alloc((size_t)MP * 256 * 2);
    u16* Qp     = (u16*)alloc((size_t)MP * 256 * 2);
    u16* gate_p = (u16*)alloc((size_t)MP * 256 * 2);
    u16* ctxd   = (u16*)alloc((size_t)MD * 256 * 2);
    u16* ctxp   = (u16*)alloc((size_t)MP * 256 * 2);
    float* cm   = (float*)alloc((size_t)MP * 8 * 4);
    float* dfc  = (float*)alloc((size_t)256 * 4);
    if (off > ws_size) return;

    pe_kernel<<<1000, 256, 0, stream>>>(pe);
    fcprep_kernel<<<1, 256, 0, stream>>>((const float*)d_in[21], (const float*)d_in[22], dfc);

    WPtrs wp;
    const int wsrc[10] = {4, 12, 14, 25, 6, 8, 10, 27, 16, 18};
    for (int m = 0; m < 10; m++) wp.w[m] = (const float*)d_in[wsrc[m]];
    wprep_kernel<<<dim3(16, 10), 256, 0, stream>>>(wp, wt);

    auto W = [&](int slot) { return wt + (size_t)slot * 65536; };

    PCfg2 p1 = {};
    p1.c0 = { nullptr,
              { { W(0), (const float*)d_in[5],  Qd,     0 },
                { W(1), (const float*)d_in[13], Kd,     0 },
                { W(2), (const float*)d_in[15], Vd,     0 },
                { W(3), (const float*)d_in[26], gate_d, 1 } } };
    p1.c1 = { nullptr,
              { { W(4), (const float*)d_in[7],  Kp,     0 },
                { W(5), (const float*)d_in[9],  Vp,     0 },
                { W(6), (const float*)d_in[11], Qp,     0 },
                { W(7), (const float*)d_in[28], gate_p, 1 } } };
    p1.x0 = drug;  p1.x1 = prot;
    p1.scale0 = scale_d;  p1.scale1 = scale_p;
    p1.pe = pe;
    proj_kernel<4><<<SG * 8 * 16, 256, 0, stream>>>(p1);

    attn_kernel<<<256, 512, 0, stream>>>(Qd, Kd, Vd, Kp, Vp, Qp,
                                         (const float*)d_in[20], ctxd, ctxp, cm);

    PCfg2 p2 = {};
    p2.c0 = { ctxd, { { W(8), (const float*)d_in[17], nullptr, 0 }, {}, {}, {} } };
    p2.c1 = { ctxp, { { W(9), (const float*)d_in[19], nullptr, 0 }, {}, {}, {} } };
    p2.x0 = drug;  p2.x1 = prot;
    p2.gate0 = gate_d;  p2.gate1 = gate_p;
    p2.cm = cm;
    p2.dfc = dfc;
    p2.wfc1 = (const float*)d_in[23];  p2.bfc1 = (const float*)d_in[24];
    p2.scale0 = scale_d;  p2.scale1 = scale_p;
    p2.pe = pe;
    p2.out = (float*)d_out;
    proj_kernel<1><<<SG * 8 * 4, 256, 0, stream>>>(p2);
}

// Round 17
// 201.895 us; speedup vs baseline: 1.5942x; 1.5942x over previous
//
#include <hip/hip_runtime.h>
#include <math.h>

typedef __attribute__((ext_vector_type(8))) short bf16x8;
typedef __attribute__((ext_vector_type(4))) float f32x4;
typedef unsigned short u16;
typedef unsigned int u32;

#define DEVFN static __device__ __forceinline__

constexpr int NB  = 32;
constexpr int DLn = 290;
constexpr int PLc = 1000;
constexpr int MD  = NB * DLn;   // 9280  = 145*64
constexpr int MP  = NB * PLc;   // 32000 = 500*64
constexpr int NSTRIP = 645;     // 64-row strips: 145 drug + 500 prot
constexpr int SPLIT  = 145;
constexpr int SG     = 81;      // ceil(645/8)

DEVFN u16 f2b(float f) {
    u32 u = __builtin_bit_cast(u32, f);
    u32 r = u + 0x7fffu + ((u >> 16) & 1u);
    return (u16)(r >> 16);
}
DEVFN float b2f(u16 s) { return __builtin_bit_cast(float, (u32)s << 16); }
DEVFN float sigm(float x) { return 1.0f / (1.0f + __expf(-x)); }
// XOR-swizzled LDS index (u16 units); stride multiple of 8 u16. 16B-aligned.
DEVFN int sw(int row, int col, int stride) { return row * stride + (col ^ ((row & 7) << 3)); }

// ---------------- PE table ----------------
__global__ void pe_kernel(float* __restrict__ pe) {
    int p = blockIdx.x, c = threadIdx.x;
    float div = __expf((float)(c & ~1) * (-9.210340371976184f / 256.0f));
    float ang = (float)p * div;
    pe[p * 256 + c] = (c & 1) ? cosf(ang) : sinf(ang);
}

// ---------------- drug fc precompute ----------------
__global__ void fcprep_kernel(const float* __restrict__ w, const float* __restrict__ b,
                              float* __restrict__ dfc) {
    int c = threadIdx.x;
    float s = b[c];
    #pragma unroll
    for (int hh = 0; hh < 8; hh++) s += 0.001f * w[hh * 256 + c];
    dfc[c] = s;
}

// ---------------- e = x + scale*pe (bf16), 4 cols/thread ----------------
__global__ __launch_bounds__(256) void eadd_kernel(
        const float* __restrict__ drug, const float* __restrict__ prot,
        const float* __restrict__ scale_d, const float* __restrict__ scale_p,
        const float* __restrict__ pe,
        u16* __restrict__ e_d, u16* __restrict__ e_p) {
    int idx = blockIdx.x * 256 + threadIdx.x;
    int r = idx >> 6, c4 = (idx & 63) * 4;
    if (r < MD) {
        int i = r % DLn;
        float s = scale_d[0];
        float4 dv = *(const float4*)&drug[(size_t)r * 256 + c4];
        float4 pv = *(const float4*)&pe[i * 256 + c4];
        u16 o[4];
        o[0] = f2b(dv.x + s * pv.x); o[1] = f2b(dv.y + s * pv.y);
        o[2] = f2b(dv.z + s * pv.z); o[3] = f2b(dv.w + s * pv.w);
        *(uint2*)&e_d[(size_t)r * 256 + c4] = *(uint2*)o;
    } else {
        int rr = r - MD;
        int j = rr % PLc;
        float s = scale_p[0];
        float4 dv = *(const float4*)&prot[(size_t)rr * 256 + c4];
        float4 pv = *(const float4*)&pe[j * 256 + c4];
        u16 o[4];
        o[0] = f2b(dv.x + s * pv.x); o[1] = f2b(dv.y + s * pv.y);
        o[2] = f2b(dv.z + s * pv.z); o[3] = f2b(dv.w + s * pv.w);
        *(uint2*)&e_p[(size_t)rr * 256 + c4] = *(uint2*)o;
    }
}

// ---------------- weight prep: WT[n][k] bf16, LDS transpose ----------------
struct WPtrs { const float* w[10]; };
__global__ __launch_bounds__(256) void wprep_kernel(WPtrs wp, u16* __restrict__ wt) {
    __shared__ u16 t[64][66];
    int m = blockIdx.y, tile = blockIdx.x;
    int k0 = (tile >> 2) * 64, n0 = (tile & 3) * 64;
    const float* w = wp.w[m];
    int r = threadIdx.x >> 6, c = threadIdx.x & 63;
    #pragma unroll
    for (int q = 0; q < 16; q++) {
        int rr = r + q * 4;
        t[rr][c] = f2b(w[(size_t)(k0 + rr) * 256 + n0 + c]);
    }
    __syncthreads();
    #pragma unroll
    for (int q = 0; q < 16; q++) {
        int rr = r + q * 4;
        wt[((size_t)m << 16) + (size_t)(n0 + rr) * 256 + k0 + c] = t[c][rr];
    }
}

// ---------------- projection: ONE 64x64 tile per block, single K=256 phase ----------------
struct PM { const u16* BT; const float* bias; u16* C; int sig; };
struct PCfg {
    const u16* Ab;
    PM m[4];
};
struct PCfg2 {
    PCfg c0, c1;
    const float* x0; const float* x1;
    const u16* gate0; const u16* gate1;
    const float* cm;
    const float* dfc;
    const float* wfc1; const float* bfc1;
    const float* scale0; const float* scale1;
    const float* pe;
    float* out;
};

template<int NM>
__global__ __launch_bounds__(256) void proj_kernel(PCfg2 cfgs) {
    const int d = blockIdx.x;
    const int x = d & 7, q = d >> 3;
    const int u  = (NM == 4) ? (q & 15) : (q & 3);
    const int sg = (NM == 4) ? (q >> 4) : (q >> 2);
    const int s = sg * 8 + x;
    if (s >= NSTRIP) return;
    const int mi = (NM == 4) ? (u >> 2) : 0;
    const int nt = (NM == 4) ? (u & 3) : u;
    const bool f1 = s < SPLIT;
    const int mt = f1 ? s : s - SPLIT;

    const u16* Ab   = f1 ? cfgs.c0.Ab : cfgs.c1.Ab;
    const u16*   BT   = f1 ? (mi==0?cfgs.c0.m[0].BT  :mi==1?cfgs.c0.m[1].BT  :mi==2?cfgs.c0.m[2].BT  :cfgs.c0.m[3].BT)
                           : (mi==0?cfgs.c1.m[0].BT  :mi==1?cfgs.c1.m[1].BT  :mi==2?cfgs.c1.m[2].BT  :cfgs.c1.m[3].BT);
    const float* bias = f1 ? (mi==0?cfgs.c0.m[0].bias:mi==1?cfgs.c0.m[1].bias:mi==2?cfgs.c0.m[2].bias:cfgs.c0.m[3].bias)
                           : (mi==0?cfgs.c1.m[0].bias:mi==1?cfgs.c1.m[1].bias:mi==2?cfgs.c1.m[2].bias:cfgs.c1.m[3].bias);
    u16*         C    = f1 ? (mi==0?cfgs.c0.m[0].C   :mi==1?cfgs.c0.m[1].C   :mi==2?cfgs.c0.m[2].C   :cfgs.c0.m[3].C)
                           : (mi==0?cfgs.c1.m[0].C   :mi==1?cfgs.c1.m[1].C   :mi==2?cfgs.c1.m[2].C   :cfgs.c1.m[3].C);
    const int    sig  = f1 ? (mi==0?cfgs.c0.m[0].sig :mi==1?cfgs.c0.m[1].sig :mi==2?cfgs.c0.m[2].sig :cfgs.c0.m[3].sig)
                           : (mi==0?cfgs.c1.m[0].sig :mi==1?cfgs.c1.m[1].sig :mi==2?cfgs.c1.m[2].sig :cfgs.c1.m[3].sig);

    __shared__ u16 Bs[64 * 256];                 // 32 KB
    __shared__ float fcb[(NM == 1) ? 2304 : 4];  // prot fc (9 KB, NM==1 only)
    const int tid = threadIdx.x;
    const int lane = tid & 63, w = tid >> 6, ln = lane & 15, g = lane >> 4;

    // ---- B tile load to regs (issued first; row permuted by nu) ----
    const int lr = tid >> 2, lc = tid & 3;
    const int nur = ((lr >> 5) & 1) * 32 + ((lr >> 2) & 3) * 8 + ((lr >> 4) & 1) * 4 + (lr & 3);
    const u16* Bp = BT + (size_t)(nt * 64 + nur) * 256 + lc * 8;
    uint4 bv[8];
    #pragma unroll
    for (int kk = 0; kk < 8; kk++) bv[kk] = *(const uint4*)(Bp + kk * 32);

    // ---- A fragments in registers: row mt*64 + w*16 + ln ----
    const int row = mt * 64 + w * 16 + ln;
    bf16x8 Af[8];
    {
        const u16* Ap = Ab + (size_t)row * 256 + g * 8;
        #pragma unroll
        for (int ks = 0; ks < 8; ks++)
            Af[ks] = *(const bf16x8*)(Ap + ks * 32);
    }

    if (NM == 1 && !f1) {
        *(float4*)&fcb[tid * 8]     = *(const float4*)&cfgs.wfc1[tid * 8];
        *(float4*)&fcb[tid * 8 + 4] = *(const float4*)&cfgs.wfc1[tid * 8 + 4];
        fcb[2048 + tid] = cfgs.bfc1[tid];
    }

    #pragma unroll
    for (int kk = 0; kk < 8; kk++)
        *(uint4*)&Bs[sw(lr, lc * 8 + kk * 32, 256)] = bv[kk];
    __syncthreads();

    // ---- compute: D = Bfrag * Afrag (C^T fragment) ----
    f32x4 acc[4] = {};
    #pragma unroll
    for (int ks = 0; ks < 8; ks++) {
        #pragma unroll
        for (int ntl = 0; ntl < 4; ntl++) {
            bf16x8 bf = *(const bf16x8*)&Bs[sw(ntl * 16 + ln, ks * 32 + g * 8, 256)];
            acc[ntl] = __builtin_amdgcn_mfma_f32_16x16x32_bf16(bf, Af[ks], acc[ntl], 0, 0, 0);
        }
    }

    // ---- epilogue: thread owns row, 16 consecutive cols (2 x 16B) ----
    const int base0 = nt * 64 + g * 8, base1 = base0 + 32;
    f32x4 b0 = *(const f32x4*)&bias[base0];
    f32x4 b1 = *(const f32x4*)&bias[base0 + 4];
    f32x4 b2 = *(const f32x4*)&bias[base1];
    f32x4 b3 = *(const f32x4*)&bias[base1 + 4];
    float v[16];
    #pragma unroll
    for (int t = 0; t < 4; t++) {
        v[t]      = acc[0][t] + b0[t];
        v[4 + t]  = acc[1][t] + b1[t];
        v[8 + t]  = acc[2][t] + b2[t];
        v[12 + t] = acc[3][t] + b3[t];
    }
    if (NM == 4) {
        if (sig) {
            #pragma unroll
            for (int t = 0; t < 16; t++) v[t] = sigm(v[t]);
        }
        u16 o[16];
        #pragma unroll
        for (int t = 0; t < 16; t++) o[t] = f2b(v[t]);
        u16* Cp = C + (size_t)row * 256;
        *(uint4*)&Cp[base0] = *(uint4*)&o[0];
        *(uint4*)&Cp[base1] = *(uint4*)&o[8];
    } else {
        // fused combine: out = e + v*gate*sigm(aw), fp32
        (void)C; (void)sig;
        const float* X     = f1 ? cfgs.x0 : cfgs.x1;
        const u16* gate    = f1 ? cfgs.gate0 : cfgs.gate1;
        const float* scale = f1 ? cfgs.scale0 : cfgs.scale1;
        const float* pe    = cfgs.pe;
        const float sc = scale[0];
        const int pos  = f1 ? (row % DLn) : (row % PLc);
        const int bidx = f1 ? (row / DLn) : (row / PLc);
        const int orow = bidx * 1290 + (f1 ? pos : 290 + pos);
        float aw[16];
        if (f1) {
            const float* dfc = cfgs.dfc;
            *(float4*)&aw[0]  = *(const float4*)&dfc[base0];
            *(float4*)&aw[4]  = *(const float4*)&dfc[base0 + 4];
            *(float4*)&aw[8]  = *(const float4*)&dfc[base1];
            *(float4*)&aw[12] = *(const float4*)&dfc[base1 + 4];
        } else {
            float cmv[8];
            float4 ca = *(const float4*)&cfgs.cm[(size_t)row * 8];
            float4 cb = *(const float4*)&cfgs.cm[(size_t)row * 8 + 4];
            cmv[0]=ca.x; cmv[1]=ca.y; cmv[2]=ca.z; cmv[3]=ca.w;
            cmv[4]=cb.x; cmv[5]=cb.y; cmv[6]=cb.z; cmv[7]=cb.w;
            #pragma unroll
            for (int t = 0; t < 16; t++) {
                const int col = (t < 8) ? (base0 + t) : (base1 + t - 8);
                float s2 = fcb[2048 + col];
                #pragma unroll
                for (int hh = 0; hh < 8; hh++) s2 += cmv[hh] * fcb[hh * 256 + col];
                aw[t] = s2;
            }
        }
        u16 ge[16];
        *(uint4*)&ge[0] = *(const uint4*)&gate[(size_t)row * 256 + base0];
        *(uint4*)&ge[8] = *(const uint4*)&gate[(size_t)row * 256 + base1];
        float outv[16];
        #pragma unroll
        for (int half = 0; half < 2; half++) {
            const int cb0 = half ? base1 : base0;
            #pragma unroll
            for (int t4 = 0; t4 < 2; t4++) {
                float4 xa = *(const float4*)&X[(size_t)row * 256 + cb0 + t4 * 4];
                float4 pa = *(const float4*)&pe[(size_t)pos * 256 + cb0 + t4 * 4];
                #pragma unroll
                for (int t = 0; t < 4; t++) {
                    const int idx = half * 8 + t4 * 4 + t;
                    float e = (&xa.x)[t] + sc * (&pa.x)[t];
                    outv[idx] = e + v[idx] * b2f(ge[idx]) * sigm(aw[idx]);
                }
            }
        }
        float* Op = cfgs.out + (size_t)orow * 256;
        *(float4*)&Op[base0]     = *(float4*)&outv[0];
        *(float4*)&Op[base0 + 4] = *(float4*)&outv[4];
        *(float4*)&Op[base1]     = *(float4*)&outv[8];
        *(float4*)&Op[base1 + 4] = *(float4*)&outv[12];
    }
}

// ---------------- attention: one block per (b,h), no-max softmax, 2 sweeps ----------------
// Q' scales folded with log2(e): S in log2 domain -> P = exp2(S) (bare v_exp_f32).
// P -> bf16 via scalar f2b (compiler-schedulable; inline-asm cvt_pk regressed, R14).
__global__ __launch_bounds__(512) void attn_kernel(
        const u16* __restrict__ Qd, const u16* __restrict__ Kd, const u16* __restrict__ Vd,
        const u16* __restrict__ Kp, const u16* __restrict__ Vp, const u16* __restrict__ Qp,
        const float* __restrict__ alpha,
        u16* __restrict__ ctx_d, u16* __restrict__ ctx_p, float* __restrict__ cm) {
    __shared__ u16 Ks[2][64 * 64];
    __shared__ union {
        struct { u16 VpT[2][32 * 64]; u16 Pm[320 * 64]; } s1;
        struct { u16 PT[64 * 320]; u16 VdT[32 * 320]; } s2;
    } U;
    __shared__ float r_l[320];
    __shared__ float colpart[8][64];

    const int bh = blockIdx.x, b = bh >> 3, h = bh & 7;
    const int tid = threadIdx.x;
    const int w = tid >> 6, lane = tid & 63, ln = lane & 15, g = lane >> 4;

    const float a = sigm(alpha[0]);
    const float inv = 0.1767766952966369f;       // 1/sqrt(32)
    const float l2e = 1.4426950408889634f;       // log2(e)
    const float sa = a * inv * l2e, sb = (1.0f - a) * inv * l2e;
    const int nmt = (w < 4) ? 3 : 2;
    const int mtsA[3] = { w, w + 8, w + 16 };

    const size_t rbd = (size_t)b * DLn * 256 + h * 32;
    const size_t rbp = (size_t)b * PLc * 256 + h * 32;

    bf16x8 Qf[3][2];
    #pragma unroll
    for (int t = 0; t < 3; t++) {
        const int i = mtsA[t] * 16 + ln;
        #pragma unroll
        for (int ks = 0; ks < 2; ks++) {
            u16 o[8] = {0,0,0,0,0,0,0,0};
            if (t < nmt && i < DLn) {
                const u16* src = (ks ? Kd : Qd) + rbd + (size_t)i * 256 + g * 8;
                const float s = ks ? sb : sa;
                uint4 v = *(const uint4*)src;
                u16 e[8]; *(uint4*)e = v;
                #pragma unroll
                for (int q = 0; q < 8; q++) o[q] = f2b(b2f(e[q]) * s);
            }
            Qf[t][ks] = *(bf16x8*)o;
        }
    }

    const int s_jj = tid >> 3, s_ch = tid & 7;
    const u16* s_src = ((s_ch >> 2) ? Qp : Kp) + rbp + (s_ch & 3) * 8;
    const int v_j = tid & 63, v_d0 = (tid >> 6) * 4;

    {
        int j = s_jj;
        uint4 kv = (j < PLc) ? *(const uint4*)(s_src + (size_t)j * 256) : make_uint4(0,0,0,0);
        uint2 vv = (v_j < PLc) ? *(const uint2*)(Vp + rbp + (size_t)v_j * 256 + v_d0) : make_uint2(0,0);
        *(uint4*)&Ks[0][sw(s_jj, s_ch * 8, 64)] = kv;
        u16 e[4]; *(uint2*)e = vv;
        #pragma unroll
        for (int q = 0; q < 4; q++) U.s1.VpT[0][sw(v_d0 + q, v_j, 64)] = e[q];
    }
    __syncthreads();

    float rs[3] = {0.f, 0.f, 0.f};
    f32x4 accd[3][2] = {};
    for (int jt = 0; jt < 16; jt++) {
        const int cur = jt & 1, j0 = jt * 64;
        const int jn = j0 + 64 + s_jj;
        uint4 kv = (jn < PLc) ? *(const uint4*)(s_src + (size_t)jn * 256) : make_uint4(0,0,0,0);
        const int vn = j0 + 64 + v_j;
        uint2 vv = (vn < PLc) ? *(const uint2*)(Vp + rbp + (size_t)vn * 256 + v_d0) : make_uint2(0,0);

        bf16x8 kf[4][2];
        #pragma unroll
        for (int js = 0; js < 4; js++)
            #pragma unroll
            for (int ks = 0; ks < 2; ks++)
                kf[js][ks] = *(const bf16x8*)&Ks[cur][sw(js * 16 + ln, ks * 32 + g * 8, 64)];

        #pragma unroll
        for (int t = 0; t < 3; t++) {
            if (t >= nmt) break;
            const int mt = mtsA[t];
            f32x4 acc[4] = {};
            #pragma unroll
            for (int ks = 0; ks < 2; ks++)
                #pragma unroll
                for (int js = 0; js < 4; js++)
                    acc[js] = __builtin_amdgcn_mfma_f32_16x16x32_bf16(kf[js][ks], Qf[t][ks], acc[js], 0, 0, 0);
            const int irow = mt * 16 + ln;
            #pragma unroll
            for (int js = 0; js < 4; js++) {
                u16 pb[4];
                float psum = 0.f;
                #pragma unroll
                for (int r = 0; r < 4; r++) {
                    float p = exp2f(acc[js][r]);
                    psum += p;
                    pb[r] = f2b(p);
                }
                rs[t] += psum;
                *(ushort4*)&U.s1.Pm[sw(irow, js * 16 + g * 4, 64)] = *(ushort4*)pb;
            }
        }
        #pragma unroll
        for (int t = 0; t < 3; t++) {
            if (t >= nmt) break;
            const int mt = mtsA[t];
            #pragma unroll
            for (int ks2 = 0; ks2 < 2; ks2++) {
                bf16x8 af = *(const bf16x8*)&U.s1.Pm[sw(mt * 16 + ln, ks2 * 32 + g * 8, 64)];
                #pragma unroll
                for (int nd = 0; nd < 2; nd++) {
                    bf16x8 bv = *(const bf16x8*)&U.s1.VpT[cur][sw(nd * 16 + ln, ks2 * 32 + g * 8, 64)];
                    accd[t][nd] = __builtin_amdgcn_mfma_f32_16x16x32_bf16(bv, af, accd[t][nd], 0, 0, 0);
                }
            }
        }
        *(uint4*)&Ks[cur ^ 1][sw(s_jj, s_ch * 8, 64)] = kv;
        {
            u16 e[4]; *(uint2*)e = vv;
            #pragma unroll
            for (int q = 0; q < 4; q++) U.s1.VpT[cur ^ 1][sw(v_d0 + q, v_j, 64)] = e[q];
        }
        __syncthreads();
    }

    #pragma unroll
    for (int t = 0; t < 3; t++) {
        float v = rs[t];
        v += __shfl_xor(v, 16);
        v += __shfl_xor(v, 32);
        rs[t] = v;
    }
    if (g == 0) {
        #pragma unroll
        for (int t = 0; t < 3; t++) {
            if (t >= nmt) break;
            const int i = mtsA[t] * 16 + ln;
            r_l[i] = (i < DLn) ? 1.0f / (rs[t] - 24.0f) : 0.0f;
        }
    }
    __syncthreads();

    #pragma unroll
    for (int t = 0; t < 3; t++) {
        if (t >= nmt) break;
        const int i = mtsA[t] * 16 + ln;
        if (i < DLn) {
            const float ri = r_l[i];
            #pragma unroll
            for (int nd = 0; nd < 2; nd++) {
                u16 o[4];
                #pragma unroll
                for (int r = 0; r < 4; r++) o[r] = f2b(accd[t][nd][r] * ri);
                *(uint2*)&ctx_d[rbd + (size_t)i * 256 + nd * 16 + g * 4] = *(uint2*)o;
            }
        }
    }
    for (int c = tid; c < 320 * 8; c += 512) {
        const int i = c >> 3, d0 = (c & 7) * 4;
        u16 o[4] = {0,0,0,0};
        if (i < DLn) {
            const float ri = r_l[i];
            uint2 v = *(const uint2*)(Vd + rbd + (size_t)i * 256 + d0);
            u16 e[4]; *(uint2*)e = v;
            #pragma unroll
            for (int q = 0; q < 4; q++) o[q] = f2b(b2f(e[q]) * ri);
        }
        #pragma unroll
        for (int q = 0; q < 4; q++) U.s2.VdT[sw(d0 + q, i, 320)] = o[q];
    }
    {
        int j = s_jj;
        uint4 kv = (j < PLc) ? *(const uint4*)(s_src + (size_t)j * 256) : make_uint4(0,0,0,0);
        *(uint4*)&Ks[0][sw(s_jj, s_ch * 8, 64)] = kv;
    }
    float rr[3][4];
    #pragma unroll
    for (int t = 0; t < 3; t++)
        #pragma unroll
        for (int r = 0; r < 4; r++)
            rr[t][r] = (t < nmt) ? r_l[mtsA[t] * 16 + g * 4 + r] : 0.0f;
    __syncthreads();

    for (int jt = 0; jt < 16; jt++) {
        const int cur = jt & 1, j0 = jt * 64;
        const int jn = j0 + 64 + s_jj;
        uint4 kv = (jn < PLc) ? *(const uint4*)(s_src + (size_t)jn * 256) : make_uint4(0,0,0,0);

        bf16x8 kf[4][2];
        #pragma unroll
        for (int js = 0; js < 4; js++)
            #pragma unroll
            for (int ks = 0; ks < 2; ks++)
                kf[js][ks] = *(const bf16x8*)&Ks[cur][sw(js * 16 + ln, ks * 32 + g * 8, 64)];

        float csl[4] = {0.f, 0.f, 0.f, 0.f};
        #pragma unroll
        for (int t = 0; t < 3; t++) {
            if (t >= nmt) break;
            const int mt = mtsA[t];
            f32x4 acc[4] = {};
            #pragma unroll
            for (int ks = 0; ks < 2; ks++)
                #pragma unroll
                for (int js = 0; js < 4; js++)
                    acc[js] = __builtin_amdgcn_mfma_f32_16x16x32_bf16(Qf[t][ks], kf[js][ks], acc[js], 0, 0, 0);
            #pragma unroll
            for (int js = 0; js < 4; js++) {
                u16 pb[4];
                #pragma unroll
                for (int r = 0; r < 4; r++) {
                    float p = exp2f(acc[js][r]);
                    csl[js] += p * rr[t][r];
                    pb[r] = f2b(p);
                }
                *(ushort4*)&U.s2.PT[sw(js * 16 + ln, mt * 16 + g * 4, 320)] = *(ushort4*)pb;
            }
        }
        #pragma unroll
        for (int js = 0; js < 4; js++) {
            float v = csl[js];
            v += __shfl_xor(v, 16);
            v += __shfl_xor(v, 32);
            csl[js] = v;
        }
        if (g == 0) {
            #pragma unroll
            for (int js = 0; js < 4; js++) colpart[w][js * 16 + ln] = csl[js];
        }
        *(uint4*)&Ks[cur ^ 1][sw(s_jj, s_ch * 8, 64)] = kv;
        __syncthreads();

        {
            const int js2 = w & 3, ds2 = w >> 2;
            f32x4 ap = {};
            #pragma unroll
            for (int k = 0; k < 10; k++) {
                bf16x8 af = *(const bf16x8*)&U.s2.PT[sw(js2 * 16 + ln, k * 32 + g * 8, 320)];
                bf16x8 bv = *(const bf16x8*)&U.s2.VdT[sw(ds2 * 16 + ln, k * 32 + g * 8, 320)];
                ap = __builtin_amdgcn_mfma_f32_16x16x32_bf16(bv, af, ap, 0, 0, 0);
            }
            const int j = j0 + js2 * 16 + ln;
            if (j < PLc) {
                u16 o[4];
                #pragma unroll
                for (int r = 0; r < 4; r++) o[r] = f2b(ap[r]);
                *(uint2*)&ctx_p[rbp + (size_t)j * 256 + ds2 * 16 + g * 4] = *(uint2*)o;
            }
        }
        if (w == 0) {
            float tot = 0.f;
            #pragma unroll
            for (int ww = 0; ww < 8; ww++) tot += colpart[ww][lane];
            const int j = j0 + lane;
            if (j < PLc) cm[(size_t)(b * PLc + j) * 8 + h] = tot * (1.0f / 290.0f);
        }
        __syncthreads();
    }
}

extern "C" void kernel_launch(void* const* d_in, const int* in_sizes, int n_in,
                              void* d_out, int out_size, void* d_ws, size_t ws_size,
                              hipStream_t stream) {
    (void)in_sizes; (void)n_in; (void)out_size;
    const float* drug    = (const float*)d_in[0];
    const float* prot    = (const float*)d_in[1];
    const float* scale_d = (const float*)d_in[2];
    const float* scale_p = (const float*)d_in[3];

    char* ws = (char*)d_ws;
    size_t off = 0;
    auto alloc = [&](size_t bytes) -> void* {
        void* p = ws + off;
        off += (bytes + 255) & ~(size_t)255;
        return p;
    };
    float* pe   = (float*)alloc((size_t)1000 * 256 * 4);
    u16* wt     = (u16*)alloc((size_t)10 * 65536 * 2);
    u16* e_d    = (u16*)alloc((size_t)MD * 256 * 2);
    u16* e_p    = (u16*)alloc((size_t)MP * 256 * 2);
    u16* Qd     = (u16*)alloc((size_t)MD * 256 * 2);
    u16* Kd     = (u16*)alloc((size_t)MD * 256 * 2);
    u16* Vd     = (u16*)alloc((size_t)MD * 256 * 2);
    u16* gate_d = (u16*)alloc((size_t)MD * 256 * 2);
    u16* Kp     = (u16*)alloc((size_t)MP * 256 * 2);
    u16* Vp     = (u16*)alloc((size_t)MP * 256 * 2);
    u16* Qp     = (u16*)alloc((size_t)MP * 256 * 2);
    u16* gate_p = (u16*)alloc((size_t)MP * 256 * 2);
    u16* ctxd   = (u16*)alloc((size_t)MD * 256 * 2);
    u16* ctxp   = (u16*)alloc((size_t)MP * 256 * 2);
    float* cm   = (float*)alloc((size_t)MP * 8 * 4);
    float* dfc  = (float*)alloc((size_t)256 * 4);
    if (off > ws_size) return;

    pe_kernel<<<1000, 256, 0, stream>>>(pe);
    fcprep_kernel<<<1, 256, 0, stream>>>((const float*)d_in[21], (const float*)d_in[22], dfc);

    WPtrs wp;
    const int wsrc[10] = {4, 12, 14, 25, 6, 8, 10, 27, 16, 18};
    for (int m = 0; m < 10; m++) wp.w[m] = (const float*)d_in[wsrc[m]];
    wprep_kernel<<<dim3(16, 10), 256, 0, stream>>>(wp, wt);

    eadd_kernel<<<(MD + MP) / 4, 256, 0, stream>>>(drug, prot, scale_d, scale_p, pe, e_d, e_p);

    auto W = [&](int slot) { return wt + (size_t)slot * 65536; };

    PCfg2 p1 = {};
    p1.c0 = { e_d,
              { { W(0), (const float*)d_in[5],  Qd,     0 },
                { W(1), (const float*)d_in[13], Kd,     0 },
                { W(2), (const float*)d_in[15], Vd,     0 },
                { W(3), (const float*)d_in[26], gate_d, 1 } } };
    p1.c1 = { e_p,
              { { W(4), (const float*)d_in[7],  Kp,     0 },
                { W(5), (const float*)d_in[9],  Vp,     0 },
                { W(6), (const float*)d_in[11], Qp,     0 },
                { W(7), (const float*)d_in[28], gate_p, 1 } } };
    proj_kernel<4><<<SG * 8 * 16, 256, 0, stream>>>(p1);

    attn_kernel<<<256, 512, 0, stream>>>(Qd, Kd, Vd, Kp, Vp, Qp,
                                         (const float*)d_in[20], ctxd, ctxp, cm);

    PCfg2 p2 = {};
    p2.c0 = { ctxd, { { W(8), (const float*)d_in[17], nullptr, 0 }, {}, {}, {} } };
    p2.c1 = { ctxp, { { W(9), (const float*)d_in[19], nullptr, 0 }, {}, {}, {} } };
    p2.x0 = drug;  p2.x1 = prot;
    p2.gate0 = gate_d;  p2.gate1 = gate_p;
    p2.cm = cm;
    p2.dfc = dfc;
    p2.wfc1 = (const float*)d_in[23];  p2.bfc1 = (const float*)d_in[24];
    p2.scale0 = scale_d;  p2.scale1 = scale_p;
    p2.pe = pe;
    p2.out = (float*)d_out;
    proj_kernel<1><<<SG * 8 * 4, 256, 0, stream>>>(p2);
}

// Round 18
// 179.828 us; speedup vs baseline: 1.7898x; 1.1227x over previous
//
#include <hip/hip_runtime.h>
#include <math.h>

typedef __attribute__((ext_vector_type(8))) short bf16x8;
typedef __attribute__((ext_vector_type(4))) float f32x4;
typedef unsigned short u16;
typedef unsigned int u32;

#define DEVFN static __device__ __forceinline__

constexpr int NB  = 32;
constexpr int DLn = 290;
constexpr int PLc = 1000;
constexpr int MD  = NB * DLn;   // 9280  = 145*64
constexpr int MP  = NB * PLc;   // 32000 = 500*64
constexpr int NSTRIP = 645;     // 64-row strips: 145 drug + 500 prot
constexpr int SPLIT  = 145;
constexpr int SG     = 81;      // ceil(645/8)

DEVFN u16 f2b(float f) {
    u32 u = __builtin_bit_cast(u32, f);
    u32 r = u + 0x7fffu + ((u >> 16) & 1u);
    return (u16)(r >> 16);
}
DEVFN float b2f(u16 s) { return __builtin_bit_cast(float, (u32)s << 16); }
DEVFN float sigm(float x) { return 1.0f / (1.0f + __expf(-x)); }
DEVFN float fexp2(float x) { return __builtin_amdgcn_exp2f(x); }   // bare v_exp_f32
// XOR-swizzled LDS index (u16 units); stride multiple of 8 u16. 16B-aligned.
DEVFN int sw(int row, int col, int stride) { return row * stride + (col ^ ((row & 7) << 3)); }

// ---------------- PE table ----------------
__global__ void pe_kernel(float* __restrict__ pe) {
    int p = blockIdx.x, c = threadIdx.x;
    float div = __expf((float)(c & ~1) * (-9.210340371976184f / 256.0f));
    float ang = (float)p * div;
    pe[p * 256 + c] = (c & 1) ? cosf(ang) : sinf(ang);
}

// ---------------- drug fc precompute ----------------
__global__ void fcprep_kernel(const float* __restrict__ w, const float* __restrict__ b,
                              float* __restrict__ dfc) {
    int c = threadIdx.x;
    float s = b[c];
    #pragma unroll
    for (int hh = 0; hh < 8; hh++) s += 0.001f * w[hh * 256 + c];
    dfc[c] = s;
}

// ---------------- e = x + scale*pe (bf16), 4 cols/thread ----------------
__global__ __launch_bounds__(256) void eadd_kernel(
        const float* __restrict__ drug, const float* __restrict__ prot,
        const float* __restrict__ scale_d, const float* __restrict__ scale_p,
        const float* __restrict__ pe,
        u16* __restrict__ e_d, u16* __restrict__ e_p) {
    int idx = blockIdx.x * 256 + threadIdx.x;
    int r = idx >> 6, c4 = (idx & 63) * 4;
    if (r < MD) {
        int i = r % DLn;
        float s = scale_d[0];
        float4 dv = *(const float4*)&drug[(size_t)r * 256 + c4];
        float4 pv = *(const float4*)&pe[i * 256 + c4];
        u16 o[4];
        o[0] = f2b(dv.x + s * pv.x); o[1] = f2b(dv.y + s * pv.y);
        o[2] = f2b(dv.z + s * pv.z); o[3] = f2b(dv.w + s * pv.w);
        *(uint2*)&e_d[(size_t)r * 256 + c4] = *(uint2*)o;
    } else {
        int rr = r - MD;
        int j = rr % PLc;
        float s = scale_p[0];
        float4 dv = *(const float4*)&prot[(size_t)rr * 256 + c4];
        float4 pv = *(const float4*)&pe[j * 256 + c4];
        u16 o[4];
        o[0] = f2b(dv.x + s * pv.x); o[1] = f2b(dv.y + s * pv.y);
        o[2] = f2b(dv.z + s * pv.z); o[3] = f2b(dv.w + s * pv.w);
        *(uint2*)&e_p[(size_t)rr * 256 + c4] = *(uint2*)o;
    }
}

// ---------------- weight prep: WT[n][k] bf16, LDS transpose ----------------
struct WPtrs { const float* w[10]; };
__global__ __launch_bounds__(256) void wprep_kernel(WPtrs wp, u16* __restrict__ wt) {
    __shared__ u16 t[64][66];
    int m = blockIdx.y, tile = blockIdx.x;
    int k0 = (tile >> 2) * 64, n0 = (tile & 3) * 64;
    const float* w = wp.w[m];
    int r = threadIdx.x >> 6, c = threadIdx.x & 63;
    #pragma unroll
    for (int q = 0; q < 16; q++) {
        int rr = r + q * 4;
        t[rr][c] = f2b(w[(size_t)(k0 + rr) * 256 + n0 + c]);
    }
    __syncthreads();
    #pragma unroll
    for (int q = 0; q < 16; q++) {
        int rr = r + q * 4;
        wt[((size_t)m << 16) + (size_t)(n0 + rr) * 256 + k0 + c] = t[c][rr];
    }
}

// ---------------- projection: ONE 64x64 tile per block, single K=256 phase ----------------
struct PM { const u16* BT; const float* bias; u16* C; int sig; };
struct PCfg {
    const u16* Ab;
    PM m[4];
};
struct PCfg2 {
    PCfg c0, c1;
    const float* x0; const float* x1;
    const u16* gate0; const u16* gate1;
    const float* cm;
    const float* dfc;
    const float* wfc1; const float* bfc1;
    const float* scale0; const float* scale1;
    const float* pe;
    float* out;
};

template<int NM>
__global__ __launch_bounds__(256) void proj_kernel(PCfg2 cfgs) {
    const int d = blockIdx.x;
    const int x = d & 7, q = d >> 3;
    const int u  = (NM == 4) ? (q & 15) : (q & 3);
    const int sg = (NM == 4) ? (q >> 4) : (q >> 2);
    const int s = sg * 8 + x;
    if (s >= NSTRIP) return;
    const int mi = (NM == 4) ? (u >> 2) : 0;
    const int nt = (NM == 4) ? (u & 3) : u;
    const bool f1 = s < SPLIT;
    const int mt = f1 ? s : s - SPLIT;

    const u16* Ab   = f1 ? cfgs.c0.Ab : cfgs.c1.Ab;
    const u16*   BT   = f1 ? (mi==0?cfgs.c0.m[0].BT  :mi==1?cfgs.c0.m[1].BT  :mi==2?cfgs.c0.m[2].BT  :cfgs.c0.m[3].BT)
                           : (mi==0?cfgs.c1.m[0].BT  :mi==1?cfgs.c1.m[1].BT  :mi==2?cfgs.c1.m[2].BT  :cfgs.c1.m[3].BT);
    const float* bias = f1 ? (mi==0?cfgs.c0.m[0].bias:mi==1?cfgs.c0.m[1].bias:mi==2?cfgs.c0.m[2].bias:cfgs.c0.m[3].bias)
                           : (mi==0?cfgs.c1.m[0].bias:mi==1?cfgs.c1.m[1].bias:mi==2?cfgs.c1.m[2].bias:cfgs.c1.m[3].bias);
    u16*         C    = f1 ? (mi==0?cfgs.c0.m[0].C   :mi==1?cfgs.c0.m[1].C   :mi==2?cfgs.c0.m[2].C   :cfgs.c0.m[3].C)
                           : (mi==0?cfgs.c1.m[0].C   :mi==1?cfgs.c1.m[1].C   :mi==2?cfgs.c1.m[2].C   :cfgs.c1.m[3].C);
    const int    sig  = f1 ? (mi==0?cfgs.c0.m[0].sig :mi==1?cfgs.c0.m[1].sig :mi==2?cfgs.c0.m[2].sig :cfgs.c0.m[3].sig)
                           : (mi==0?cfgs.c1.m[0].sig :mi==1?cfgs.c1.m[1].sig :mi==2?cfgs.c1.m[2].sig :cfgs.c1.m[3].sig);

    __shared__ u16 Bs[64 * 256];                 // 32 KB
    __shared__ float fcb[(NM == 1) ? 2304 : 4];  // prot fc (9 KB, NM==1 only)
    const int tid = threadIdx.x;
    const int lane = tid & 63, w = tid >> 6, ln = lane & 15, g = lane >> 4;

    // ---- B tile load to regs (issued first; row permuted by nu) ----
    const int lr = tid >> 2, lc = tid & 3;
    const int nur = ((lr >> 5) & 1) * 32 + ((lr >> 2) & 3) * 8 + ((lr >> 4) & 1) * 4 + (lr & 3);
    const u16* Bp = BT + (size_t)(nt * 64 + nur) * 256 + lc * 8;
    uint4 bv[8];
    #pragma unroll
    for (int kk = 0; kk < 8; kk++) bv[kk] = *(const uint4*)(Bp + kk * 32);

    // ---- A fragments in registers: row mt*64 + w*16 + ln ----
    const int row = mt * 64 + w * 16 + ln;
    bf16x8 Af[8];
    {
        const u16* Ap = Ab + (size_t)row * 256 + g * 8;
        #pragma unroll
        for (int ks = 0; ks < 8; ks++)
            Af[ks] = *(const bf16x8*)(Ap + ks * 32);
    }

    if (NM == 1 && !f1) {
        *(float4*)&fcb[tid * 8]     = *(const float4*)&cfgs.wfc1[tid * 8];
        *(float4*)&fcb[tid * 8 + 4] = *(const float4*)&cfgs.wfc1[tid * 8 + 4];
        fcb[2048 + tid] = cfgs.bfc1[tid];
    }

    #pragma unroll
    for (int kk = 0; kk < 8; kk++)
        *(uint4*)&Bs[sw(lr, lc * 8 + kk * 32, 256)] = bv[kk];
    __syncthreads();

    // ---- compute: D = Bfrag * Afrag (C^T fragment) ----
    f32x4 acc[4] = {};
    #pragma unroll
    for (int ks = 0; ks < 8; ks++) {
        #pragma unroll
        for (int ntl = 0; ntl < 4; ntl++) {
            bf16x8 bf = *(const bf16x8*)&Bs[sw(ntl * 16 + ln, ks * 32 + g * 8, 256)];
            acc[ntl] = __builtin_amdgcn_mfma_f32_16x16x32_bf16(bf, Af[ks], acc[ntl], 0, 0, 0);
        }
    }

    // ---- epilogue: thread owns row, 16 consecutive cols (2 x 16B) ----
    const int base0 = nt * 64 + g * 8, base1 = base0 + 32;
    f32x4 b0 = *(const f32x4*)&bias[base0];
    f32x4 b1 = *(const f32x4*)&bias[base0 + 4];
    f32x4 b2 = *(const f32x4*)&bias[base1];
    f32x4 b3 = *(const f32x4*)&bias[base1 + 4];
    float v[16];
    #pragma unroll
    for (int t = 0; t < 4; t++) {
        v[t]      = acc[0][t] + b0[t];
        v[4 + t]  = acc[1][t] + b1[t];
        v[8 + t]  = acc[2][t] + b2[t];
        v[12 + t] = acc[3][t] + b3[t];
    }
    if (NM == 4) {
        if (sig) {
            #pragma unroll
            for (int t = 0; t < 16; t++) v[t] = sigm(v[t]);
        }
        u16 o[16];
        #pragma unroll
        for (int t = 0; t < 16; t++) o[t] = f2b(v[t]);
        u16* Cp = C + (size_t)row * 256;
        *(uint4*)&Cp[base0] = *(uint4*)&o[0];
        *(uint4*)&Cp[base1] = *(uint4*)&o[8];
    } else {
        // fused combine: out = e + v*gate*sigm(aw), fp32
        (void)C; (void)sig;
        const float* X     = f1 ? cfgs.x0 : cfgs.x1;
        const u16* gate    = f1 ? cfgs.gate0 : cfgs.gate1;
        const float* scale = f1 ? cfgs.scale0 : cfgs.scale1;
        const float* pe    = cfgs.pe;
        const float sc = scale[0];
        const int pos  = f1 ? (row % DLn) : (row % PLc);
        const int bidx = f1 ? (row / DLn) : (row / PLc);
        const int orow = bidx * 1290 + (f1 ? pos : 290 + pos);
        float aw[16];
        if (f1) {
            const float* dfc = cfgs.dfc;
            *(float4*)&aw[0]  = *(const float4*)&dfc[base0];
            *(float4*)&aw[4]  = *(const float4*)&dfc[base0 + 4];
            *(float4*)&aw[8]  = *(const float4*)&dfc[base1];
            *(float4*)&aw[12] = *(const float4*)&dfc[base1 + 4];
        } else {
            float cmv[8];
            float4 ca = *(const float4*)&cfgs.cm[(size_t)row * 8];
            float4 cb = *(const float4*)&cfgs.cm[(size_t)row * 8 + 4];
            cmv[0]=ca.x; cmv[1]=ca.y; cmv[2]=ca.z; cmv[3]=ca.w;
            cmv[4]=cb.x; cmv[5]=cb.y; cmv[6]=cb.z; cmv[7]=cb.w;
            #pragma unroll
            for (int t = 0; t < 16; t++) {
                const int col = (t < 8) ? (base0 + t) : (base1 + t - 8);
                float s2 = fcb[2048 + col];
                #pragma unroll
                for (int hh = 0; hh < 8; hh++) s2 += cmv[hh] * fcb[hh * 256 + col];
                aw[t] = s2;
            }
        }
        u16 ge[16];
        *(uint4*)&ge[0] = *(const uint4*)&gate[(size_t)row * 256 + base0];
        *(uint4*)&ge[8] = *(const uint4*)&gate[(size_t)row * 256 + base1];
        float outv[16];
        #pragma unroll
        for (int half = 0; half < 2; half++) {
            const int cb0 = half ? base1 : base0;
            #pragma unroll
            for (int t4 = 0; t4 < 2; t4++) {
                float4 xa = *(const float4*)&X[(size_t)row * 256 + cb0 + t4 * 4];
                float4 pa = *(const float4*)&pe[(size_t)pos * 256 + cb0 + t4 * 4];
                #pragma unroll
                for (int t = 0; t < 4; t++) {
                    const int idx = half * 8 + t4 * 4 + t;
                    float e = (&xa.x)[t] + sc * (&pa.x)[t];
                    outv[idx] = e + v[idx] * b2f(ge[idx]) * sigm(aw[idx]);
                }
            }
        }
        float* Op = cfgs.out + (size_t)orow * 256;
        *(float4*)&Op[base0]     = *(float4*)&outv[0];
        *(float4*)&Op[base0 + 4] = *(float4*)&outv[4];
        *(float4*)&Op[base1]     = *(float4*)&outv[8];
        *(float4*)&Op[base1 + 4] = *(float4*)&outv[12];
    }
}

// ---------------- attention: one block per (b,h), no-max softmax, 2 sweeps ----------------
// Q' scales folded with log2(e): S in log2 domain -> P = 2^S via
// __builtin_amdgcn_exp2f (bare v_exp_f32; exp2f libm call regressed in R16).
// P -> bf16 via scalar f2b (inline-asm cvt_pk regressed in R14).
__global__ __launch_bounds__(512) void attn_kernel(
        const u16* __restrict__ Qd, const u16* __restrict__ Kd, const u16* __restrict__ Vd,
        const u16* __restrict__ Kp, const u16* __restrict__ Vp, const u16* __restrict__ Qp,
        const float* __restrict__ alpha,
        u16* __restrict__ ctx_d, u16* __restrict__ ctx_p, float* __restrict__ cm) {
    __shared__ u16 Ks[2][64 * 64];
    __shared__ union {
        struct { u16 VpT[2][32 * 64]; u16 Pm[320 * 64]; } s1;
        struct { u16 PT[64 * 320]; u16 VdT[32 * 320]; } s2;
    } U;
    __shared__ float r_l[320];
    __shared__ float colpart[8][64];

    const int bh = blockIdx.x, b = bh >> 3, h = bh & 7;
    const int tid = threadIdx.x;
    const int w = tid >> 6, lane = tid & 63, ln = lane & 15, g = lane >> 4;

    const float a = sigm(alpha[0]);
    const float inv = 0.1767766952966369f;       // 1/sqrt(32)
    const float l2e = 1.4426950408889634f;       // log2(e)
    const float sa = a * inv * l2e, sb = (1.0f - a) * inv * l2e;
    const int nmt = (w < 4) ? 3 : 2;
    const int mtsA[3] = { w, w + 8, w + 16 };

    const size_t rbd = (size_t)b * DLn * 256 + h * 32;
    const size_t rbp = (size_t)b * PLc * 256 + h * 32;

    bf16x8 Qf[3][2];
    #pragma unroll
    for (int t = 0; t < 3; t++) {
        const int i = mtsA[t] * 16 + ln;
        #pragma unroll
        for (int ks = 0; ks < 2; ks++) {
            u16 o[8] = {0,0,0,0,0,0,0,0};
            if (t < nmt && i < DLn) {
                const u16* src = (ks ? Kd : Qd) + rbd + (size_t)i * 256 + g * 8;
                const float s = ks ? sb : sa;
                uint4 v = *(const uint4*)src;
                u16 e[8]; *(uint4*)e = v;
                #pragma unroll
                for (int q = 0; q < 8; q++) o[q] = f2b(b2f(e[q]) * s);
            }
            Qf[t][ks] = *(bf16x8*)o;
        }
    }

    const int s_jj = tid >> 3, s_ch = tid & 7;
    const u16* s_src = ((s_ch >> 2) ? Qp : Kp) + rbp + (s_ch & 3) * 8;
    const int v_j = tid & 63, v_d0 = (tid >> 6) * 4;

    {
        int j = s_jj;
        uint4 kv = (j < PLc) ? *(const uint4*)(s_src + (size_t)j * 256) : make_uint4(0,0,0,0);
        uint2 vv = (v_j < PLc) ? *(const uint2*)(Vp + rbp + (size_t)v_j * 256 + v_d0) : make_uint2(0,0);
        *(uint4*)&Ks[0][sw(s_jj, s_ch * 8, 64)] = kv;
        u16 e[4]; *(uint2*)e = vv;
        #pragma unroll
        for (int q = 0; q < 4; q++) U.s1.VpT[0][sw(v_d0 + q, v_j, 64)] = e[q];
    }
    __syncthreads();

    float rs[3] = {0.f, 0.f, 0.f};
    f32x4 accd[3][2] = {};
    for (int jt = 0; jt < 16; jt++) {
        const int cur = jt & 1, j0 = jt * 64;
        const int jn = j0 + 64 + s_jj;
        uint4 kv = (jn < PLc) ? *(const uint4*)(s_src + (size_t)jn * 256) : make_uint4(0,0,0,0);
        const int vn = j0 + 64 + v_j;
        uint2 vv = (vn < PLc) ? *(const uint2*)(Vp + rbp + (size_t)vn * 256 + v_d0) : make_uint2(0,0);

        bf16x8 kf[4][2];
        #pragma unroll
        for (int js = 0; js < 4; js++)
            #pragma unroll
            for (int ks = 0; ks < 2; ks++)
                kf[js][ks] = *(const bf16x8*)&Ks[cur][sw(js * 16 + ln, ks * 32 + g * 8, 64)];

        #pragma unroll
        for (int t = 0; t < 3; t++) {
            if (t >= nmt) break;
            const int mt = mtsA[t];
            f32x4 acc[4] = {};
            #pragma unroll
            for (int ks = 0; ks < 2; ks++)
                #pragma unroll
                for (int js = 0; js < 4; js++)
                    acc[js] = __builtin_amdgcn_mfma_f32_16x16x32_bf16(kf[js][ks], Qf[t][ks], acc[js], 0, 0, 0);
            const int irow = mt * 16 + ln;
            #pragma unroll
            for (int js = 0; js < 4; js++) {
                u16 pb[4];
                float psum = 0.f;
                #pragma unroll
                for (int r = 0; r < 4; r++) {
                    float p = fexp2(acc[js][r]);
                    psum += p;
                    pb[r] = f2b(p);
                }
                rs[t] += psum;
                *(ushort4*)&U.s1.Pm[sw(irow, js * 16 + g * 4, 64)] = *(ushort4*)pb;
            }
        }
        #pragma unroll
        for (int t = 0; t < 3; t++) {
            if (t >= nmt) break;
            const int mt = mtsA[t];
            #pragma unroll
            for (int ks2 = 0; ks2 < 2; ks2++) {
                bf16x8 af = *(const bf16x8*)&U.s1.Pm[sw(mt * 16 + ln, ks2 * 32 + g * 8, 64)];
                #pragma unroll
                for (int nd = 0; nd < 2; nd++) {
                    bf16x8 bv = *(const bf16x8*)&U.s1.VpT[cur][sw(nd * 16 + ln, ks2 * 32 + g * 8, 64)];
                    accd[t][nd] = __builtin_amdgcn_mfma_f32_16x16x32_bf16(bv, af, accd[t][nd], 0, 0, 0);
                }
            }
        }
        *(uint4*)&Ks[cur ^ 1][sw(s_jj, s_ch * 8, 64)] = kv;
        {
            u16 e[4]; *(uint2*)e = vv;
            #pragma unroll
            for (int q = 0; q < 4; q++) U.s1.VpT[cur ^ 1][sw(v_d0 + q, v_j, 64)] = e[q];
        }
        __syncthreads();
    }

    #pragma unroll
    for (int t = 0; t < 3; t++) {
        float v = rs[t];
        v += __shfl_xor(v, 16);
        v += __shfl_xor(v, 32);
        rs[t] = v;
    }
    if (g == 0) {
        #pragma unroll
        for (int t = 0; t < 3; t++) {
            if (t >= nmt) break;
            const int i = mtsA[t] * 16 + ln;
            r_l[i] = (i < DLn) ? 1.0f / (rs[t] - 24.0f) : 0.0f;
        }
    }
    __syncthreads();

    #pragma unroll
    for (int t = 0; t < 3; t++) {
        if (t >= nmt) break;
        const int i = mtsA[t] * 16 + ln;
        if (i < DLn) {
            const float ri = r_l[i];
            #pragma unroll
            for (int nd = 0; nd < 2; nd++) {
                u16 o[4];
                #pragma unroll
                for (int r = 0; r < 4; r++) o[r] = f2b(accd[t][nd][r] * ri);
                *(uint2*)&ctx_d[rbd + (size_t)i * 256 + nd * 16 + g * 4] = *(uint2*)o;
            }
        }
    }
    for (int c = tid; c < 320 * 8; c += 512) {
        const int i = c >> 3, d0 = (c & 7) * 4;
        u16 o[4] = {0,0,0,0};
        if (i < DLn) {
            const float ri = r_l[i];
            uint2 v = *(const uint2*)(Vd + rbd + (size_t)i * 256 + d0);
            u16 e[4]; *(uint2*)e = v;
            #pragma unroll
            for (int q = 0; q < 4; q++) o[q] = f2b(b2f(e[q]) * ri);
        }
        #pragma unroll
        for (int q = 0; q < 4; q++) U.s2.VdT[sw(d0 + q, i, 320)] = o[q];
    }
    {
        int j = s_jj;
        uint4 kv = (j < PLc) ? *(const uint4*)(s_src + (size_t)j * 256) : make_uint4(0,0,0,0);
        *(uint4*)&Ks[0][sw(s_jj, s_ch * 8, 64)] = kv;
    }
    float rr[3][4];
    #pragma unroll
    for (int t = 0; t < 3; t++)
        #pragma unroll
        for (int r = 0; r < 4; r++)
            rr[t][r] = (t < nmt) ? r_l[mtsA[t] * 16 + g * 4 + r] : 0.0f;
    __syncthreads();

    for (int jt = 0; jt < 16; jt++) {
        const int cur = jt & 1, j0 = jt * 64;
        const int jn = j0 + 64 + s_jj;
        uint4 kv = (jn < PLc) ? *(const uint4*)(s_src + (size_t)jn * 256) : make_uint4(0,0,0,0);

        bf16x8 kf[4][2];
        #pragma unroll
        for (int js = 0; js < 4; js++)
            #pragma unroll
            for (int ks = 0; ks < 2; ks++)
                kf[js][ks] = *(const bf16x8*)&Ks[cur][sw(js * 16 + ln, ks * 32 + g * 8, 64)];

        float csl[4] = {0.f, 0.f, 0.f, 0.f};
        #pragma unroll
        for (int t = 0; t < 3; t++) {
            if (t >= nmt) break;
            const int mt = mtsA[t];
            f32x4 acc[4] = {};
            #pragma unroll
            for (int ks = 0; ks < 2; ks++)
                #pragma unroll
                for (int js = 0; js < 4; js++)
                    acc[js] = __builtin_amdgcn_mfma_f32_16x16x32_bf16(Qf[t][ks], kf[js][ks], acc[js], 0, 0, 0);
            #pragma unroll
            for (int js = 0; js < 4; js++) {
                u16 pb[4];
                #pragma unroll
                for (int r = 0; r < 4; r++) {
                    float p = fexp2(acc[js][r]);
                    csl[js] += p * rr[t][r];
                    pb[r] = f2b(p);
                }
                *(ushort4*)&U.s2.PT[sw(js * 16 + ln, mt * 16 + g * 4, 320)] = *(ushort4*)pb;
            }
        }
        #pragma unroll
        for (int js = 0; js < 4; js++) {
            float v = csl[js];
            v += __shfl_xor(v, 16);
            v += __shfl_xor(v, 32);
            csl[js] = v;
        }
        if (g == 0) {
            #pragma unroll
            for (int js = 0; js < 4; js++) colpart[w][js * 16 + ln] = csl[js];
        }
        *(uint4*)&Ks[cur ^ 1][sw(s_jj, s_ch * 8, 64)] = kv;
        __syncthreads();

        {
            const int js2 = w & 3, ds2 = w >> 2;
            f32x4 ap = {};
            #pragma unroll
            for (int k = 0; k < 10; k++) {
                bf16x8 af = *(const bf16x8*)&U.s2.PT[sw(js2 * 16 + ln, k * 32 + g * 8, 320)];
                bf16x8 bv = *(const bf16x8*)&U.s2.VdT[sw(ds2 * 16 + ln, k * 32 + g * 8, 320)];
                ap = __builtin_amdgcn_mfma_f32_16x16x32_bf16(bv, af, ap, 0, 0, 0);
            }
            const int j = j0 + js2 * 16 + ln;
            if (j < PLc) {
                u16 o[4];
                #pragma unroll
                for (int r = 0; r < 4; r++) o[r] = f2b(ap[r]);
                *(uint2*)&ctx_p[rbp + (size_t)j * 256 + ds2 * 16 + g * 4] = *(uint2*)o;
            }
        }
        if (w == 0) {
            float tot = 0.f;
            #pragma unroll
            for (int ww = 0; ww < 8; ww++) tot += colpart[ww][lane];
            const int j = j0 + lane;
            if (j < PLc) cm[(size_t)(b * PLc + j) * 8 + h] = tot * (1.0f / 290.0f);
        }
        __syncthreads();
    }
}

extern "C" void kernel_launch(void* const* d_in, const int* in_sizes, int n_in,
                              void* d_out, int out_size, void* d_ws, size_t ws_size,
                              hipStream_t stream) {
    (void)in_sizes; (void)n_in; (void)out_size;
    const float* drug    = (const float*)d_in[0];
    const float* prot    = (const float*)d_in[1];
    const float* scale_d = (const float*)d_in[2];
    const float* scale_p = (const float*)d_in[3];

    char* ws = (char*)d_ws;
    size_t off = 0;
    auto alloc = [&](size_t bytes) -> void* {
        void* p = ws + off;
        off += (bytes + 255) & ~(size_t)255;
        return p;
    };
    float* pe   = (float*)alloc((size_t)1000 * 256 * 4);
    u16* wt     = (u16*)alloc((size_t)10 * 65536 * 2);
    u16* e_d    = (u16*)alloc((size_t)MD * 256 * 2);
    u16* e_p    = (u16*)alloc((size_t)MP * 256 * 2);
    u16* Qd     = (u16*)alloc((size_t)MD * 256 * 2);
    u16* Kd     = (u16*)alloc((size_t)MD * 256 * 2);
    u16* Vd     = (u16*)alloc((size_t)MD * 256 * 2);
    u16* gate_d = (u16*)alloc((size_t)MD * 256 * 2);
    u16* Kp     = (u16*)alloc((size_t)MP * 256 * 2);
    u16* Vp     = (u16*)alloc((size_t)MP * 256 * 2);
    u16* Qp     = (u16*)alloc((size_t)MP * 256 * 2);
    u16* gate_p = (u16*)alloc((size_t)MP * 256 * 2);
    u16* ctxd   = (u16*)alloc((size_t)MD * 256 * 2);
    u16* ctxp   = (u16*)alloc((size_t)MP * 256 * 2);
    float* cm   = (float*)alloc((size_t)MP * 8 * 4);
    float* dfc  = (float*)alloc((size_t)256 * 4);
    if (off > ws_size) return;

    pe_kernel<<<1000, 256, 0, stream>>>(pe);
    fcprep_kernel<<<1, 256, 0, stream>>>((const float*)d_in[21], (const float*)d_in[22], dfc);

    WPtrs wp;
    const int wsrc[10] = {4, 12, 14, 25, 6, 8, 10, 27, 16, 18};
    for (int m = 0; m < 10; m++) wp.w[m] = (const float*)d_in[wsrc[m]];
    wprep_kernel<<<dim3(16, 10), 256, 0, stream>>>(wp, wt);

    eadd_kernel<<<(MD + MP) / 4, 256, 0, stream>>>(drug, prot, scale_d, scale_p, pe, e_d, e_p);

    auto W = [&](int slot) { return wt + (size_t)slot * 65536; };

    PCfg2 p1 = {};
    p1.c0 = { e_d,
              { { W(0), (const float*)d_in[5],  Qd,     0 },
                { W(1), (const float*)d_in[13], Kd,     0 },
                { W(2), (const float*)d_in[15], Vd,     0 },
                { W(3), (const float*)d_in[26], gate_d, 1 } } };
    p1.c1 = { e_p,
              { { W(4), (const float*)d_in[7],  Kp,     0 },
                { W(5), (const float*)d_in[9],  Vp,     0 },
                { W(6), (const float*)d_in[11], Qp,     0 },
                { W(7), (const float*)d_in[28], gate_p, 1 } } };
    proj_kernel<4><<<SG * 8 * 16, 256, 0, stream>>>(p1);

    attn_kernel<<<256, 512, 0, stream>>>(Qd, Kd, Vd, Kp, Vp, Qp,
                                         (const float*)d_in[20], ctxd, ctxp, cm);

    PCfg2 p2 = {};
    p2.c0 = { ctxd, { { W(8), (const float*)d_in[17], nullptr, 0 }, {}, {}, {} } };
    p2.c1 = { ctxp, { { W(9), (const float*)d_in[19], nullptr, 0 }, {}, {}, {} } };
    p2.x0 = drug;  p2.x1 = prot;
    p2.gate0 = gate_d;  p2.gate1 = gate_p;
    p2.cm = cm;
    p2.dfc = dfc;
    p2.wfc1 = (const float*)d_in[23];  p2.bfc1 = (const float*)d_in[24];
    p2.scale0 = scale_d;  p2.scale1 = scale_p;
    p2.pe = pe;
    p2.out = (float*)d_out;
    proj_kernel<1><<<SG * 8 * 4, 256, 0, stream>>>(p2);
}

// Round 19
// 174.282 us; speedup vs baseline: 1.8468x; 1.0318x over previous
//
#include <hip/hip_runtime.h>
#include <math.h>

typedef __attribute__((ext_vector_type(8))) short bf16x8;
typedef __attribute__((ext_vector_type(4))) float f32x4;
typedef unsigned short u16;
typedef unsigned int u32;

#define DEVFN static __device__ __forceinline__

constexpr int NB  = 32;
constexpr int DLn = 290;
constexpr int PLc = 1000;
constexpr int MD  = NB * DLn;   // 9280  = 145*64
constexpr int MP  = NB * PLc;   // 32000 = 500*64
constexpr int NSTRIP = 645;     // 64-row strips: 145 drug + 500 prot
constexpr int SPLIT  = 145;
constexpr int SG     = 81;      // ceil(645/8)

DEVFN u16 f2b(float f) {
    u32 u = __builtin_bit_cast(u32, f);
    u32 r = u + 0x7fffu + ((u >> 16) & 1u);
    return (u16)(r >> 16);
}
// native conversion: compiler lowers fptrunc to v_cvt_pk_bf16_f32 (1 op, RNE)
DEVFN u16 f2bh(float f) { __bf16 h = (__bf16)f; return __builtin_bit_cast(u16, h); }
DEVFN float b2f(u16 s) { return __builtin_bit_cast(float, (u32)s << 16); }
DEVFN float sigm(float x) { return 1.0f / (1.0f + __expf(-x)); }
DEVFN float fexp2(float x) { return __builtin_amdgcn_exp2f(x); }   // bare v_exp_f32
// XOR-swizzled LDS index (u16 units); stride multiple of 8 u16. 16B-aligned.
DEVFN int sw(int row, int col, int stride) { return row * stride + (col ^ ((row & 7) << 3)); }

// ---------------- PE table ----------------
__global__ void pe_kernel(float* __restrict__ pe) {
    int p = blockIdx.x, c = threadIdx.x;
    float div = __expf((float)(c & ~1) * (-9.210340371976184f / 256.0f));
    float ang = (float)p * div;
    pe[p * 256 + c] = (c & 1) ? cosf(ang) : sinf(ang);
}

// ---------------- drug fc precompute ----------------
__global__ void fcprep_kernel(const float* __restrict__ w, const float* __restrict__ b,
                              float* __restrict__ dfc) {
    int c = threadIdx.x;
    float s = b[c];
    #pragma unroll
    for (int hh = 0; hh < 8; hh++) s += 0.001f * w[hh * 256 + c];
    dfc[c] = s;
}

// ---------------- e = x + scale*pe (bf16), 4 cols/thread ----------------
__global__ __launch_bounds__(256) void eadd_kernel(
        const float* __restrict__ drug, const float* __restrict__ prot,
        const float* __restrict__ scale_d, const float* __restrict__ scale_p,
        const float* __restrict__ pe,
        u16* __restrict__ e_d, u16* __restrict__ e_p) {
    int idx = blockIdx.x * 256 + threadIdx.x;
    int r = idx >> 6, c4 = (idx & 63) * 4;
    if (r < MD) {
        int i = r % DLn;
        float s = scale_d[0];
        float4 dv = *(const float4*)&drug[(size_t)r * 256 + c4];
        float4 pv = *(const float4*)&pe[i * 256 + c4];
        u16 o[4];
        o[0] = f2b(dv.x + s * pv.x); o[1] = f2b(dv.y + s * pv.y);
        o[2] = f2b(dv.z + s * pv.z); o[3] = f2b(dv.w + s * pv.w);
        *(uint2*)&e_d[(size_t)r * 256 + c4] = *(uint2*)o;
    } else {
        int rr = r - MD;
        int j = rr % PLc;
        float s = scale_p[0];
        float4 dv = *(const float4*)&prot[(size_t)rr * 256 + c4];
        float4 pv = *(const float4*)&pe[j * 256 + c4];
        u16 o[4];
        o[0] = f2b(dv.x + s * pv.x); o[1] = f2b(dv.y + s * pv.y);
        o[2] = f2b(dv.z + s * pv.z); o[3] = f2b(dv.w + s * pv.w);
        *(uint2*)&e_p[(size_t)rr * 256 + c4] = *(uint2*)o;
    }
}

// ---------------- weight prep: WT[n][k] bf16, LDS transpose ----------------
struct WPtrs { const float* w[10]; };
__global__ __launch_bounds__(256) void wprep_kernel(WPtrs wp, u16* __restrict__ wt) {
    __shared__ u16 t[64][66];
    int m = blockIdx.y, tile = blockIdx.x;
    int k0 = (tile >> 2) * 64, n0 = (tile & 3) * 64;
    const float* w = wp.w[m];
    int r = threadIdx.x >> 6, c = threadIdx.x & 63;
    #pragma unroll
    for (int q = 0; q < 16; q++) {
        int rr = r + q * 4;
        t[rr][c] = f2b(w[(size_t)(k0 + rr) * 256 + n0 + c]);
    }
    __syncthreads();
    #pragma unroll
    for (int q = 0; q < 16; q++) {
        int rr = r + q * 4;
        wt[((size_t)m << 16) + (size_t)(n0 + rr) * 256 + k0 + c] = t[c][rr];
    }
}

// ---------------- projection: ONE 64x64 tile per block, single K=256 phase ----------------
struct PM { const u16* BT; const float* bias; u16* C; int sig; };
struct PCfg {
    const u16* Ab;
    PM m[4];
};
struct PCfg2 {
    PCfg c0, c1;
    const float* x0; const float* x1;
    const u16* gate0; const u16* gate1;
    const float* cm;
    const float* dfc;
    const float* wfc1; const float* bfc1;
    const float* scale0; const float* scale1;
    const float* pe;
    float* out;
};

template<int NM>
__global__ __launch_bounds__(256) void proj_kernel(PCfg2 cfgs) {
    const int d = blockIdx.x;
    const int x = d & 7, q = d >> 3;
    const int u  = (NM == 4) ? (q & 15) : (q & 3);
    const int sg = (NM == 4) ? (q >> 4) : (q >> 2);
    const int s = sg * 8 + x;
    if (s >= NSTRIP) return;
    const int mi = (NM == 4) ? (u >> 2) : 0;
    const int nt = (NM == 4) ? (u & 3) : u;
    const bool f1 = s < SPLIT;
    const int mt = f1 ? s : s - SPLIT;

    const u16* Ab   = f1 ? cfgs.c0.Ab : cfgs.c1.Ab;
    const u16*   BT   = f1 ? (mi==0?cfgs.c0.m[0].BT  :mi==1?cfgs.c0.m[1].BT  :mi==2?cfgs.c0.m[2].BT  :cfgs.c0.m[3].BT)
                           : (mi==0?cfgs.c1.m[0].BT  :mi==1?cfgs.c1.m[1].BT  :mi==2?cfgs.c1.m[2].BT  :cfgs.c1.m[3].BT);
    const float* bias = f1 ? (mi==0?cfgs.c0.m[0].bias:mi==1?cfgs.c0.m[1].bias:mi==2?cfgs.c0.m[2].bias:cfgs.c0.m[3].bias)
                           : (mi==0?cfgs.c1.m[0].bias:mi==1?cfgs.c1.m[1].bias:mi==2?cfgs.c1.m[2].bias:cfgs.c1.m[3].bias);
    u16*         C    = f1 ? (mi==0?cfgs.c0.m[0].C   :mi==1?cfgs.c0.m[1].C   :mi==2?cfgs.c0.m[2].C   :cfgs.c0.m[3].C)
                           : (mi==0?cfgs.c1.m[0].C   :mi==1?cfgs.c1.m[1].C   :mi==2?cfgs.c1.m[2].C   :cfgs.c1.m[3].C);
    const int    sig  = f1 ? (mi==0?cfgs.c0.m[0].sig :mi==1?cfgs.c0.m[1].sig :mi==2?cfgs.c0.m[2].sig :cfgs.c0.m[3].sig)
                           : (mi==0?cfgs.c1.m[0].sig :mi==1?cfgs.c1.m[1].sig :mi==2?cfgs.c1.m[2].sig :cfgs.c1.m[3].sig);

    __shared__ u16 Bs[64 * 256];                 // 32 KB
    __shared__ float fcb[(NM == 1) ? 2304 : 4];  // prot fc (9 KB, NM==1 only)
    const int tid = threadIdx.x;
    const int lane = tid & 63, w = tid >> 6, ln = lane & 15, g = lane >> 4;

    // ---- B tile load to regs (issued first; row permuted by nu) ----
    const int lr = tid >> 2, lc = tid & 3;
    const int nur = ((lr >> 5) & 1) * 32 + ((lr >> 2) & 3) * 8 + ((lr >> 4) & 1) * 4 + (lr & 3);
    const u16* Bp = BT + (size_t)(nt * 64 + nur) * 256 + lc * 8;
    uint4 bv[8];
    #pragma unroll
    for (int kk = 0; kk < 8; kk++) bv[kk] = *(const uint4*)(Bp + kk * 32);

    // ---- A fragments in registers: row mt*64 + w*16 + ln ----
    const int row = mt * 64 + w * 16 + ln;
    bf16x8 Af[8];
    {
        const u16* Ap = Ab + (size_t)row * 256 + g * 8;
        #pragma unroll
        for (int ks = 0; ks < 8; ks++)
            Af[ks] = *(const bf16x8*)(Ap + ks * 32);
    }

    if (NM == 1 && !f1) {
        *(float4*)&fcb[tid * 8]     = *(const float4*)&cfgs.wfc1[tid * 8];
        *(float4*)&fcb[tid * 8 + 4] = *(const float4*)&cfgs.wfc1[tid * 8 + 4];
        fcb[2048 + tid] = cfgs.bfc1[tid];
    }

    #pragma unroll
    for (int kk = 0; kk < 8; kk++)
        *(uint4*)&Bs[sw(lr, lc * 8 + kk * 32, 256)] = bv[kk];
    __syncthreads();

    // ---- compute: D = Bfrag * Afrag (C^T fragment) ----
    f32x4 acc[4] = {};
    #pragma unroll
    for (int ks = 0; ks < 8; ks++) {
        #pragma unroll
        for (int ntl = 0; ntl < 4; ntl++) {
            bf16x8 bf = *(const bf16x8*)&Bs[sw(ntl * 16 + ln, ks * 32 + g * 8, 256)];
            acc[ntl] = __builtin_amdgcn_mfma_f32_16x16x32_bf16(bf, Af[ks], acc[ntl], 0, 0, 0);
        }
    }

    // ---- epilogue: thread owns row, 16 consecutive cols (2 x 16B) ----
    const int base0 = nt * 64 + g * 8, base1 = base0 + 32;
    f32x4 b0 = *(const f32x4*)&bias[base0];
    f32x4 b1 = *(const f32x4*)&bias[base0 + 4];
    f32x4 b2 = *(const f32x4*)&bias[base1];
    f32x4 b3 = *(const f32x4*)&bias[base1 + 4];
    float v[16];
    #pragma unroll
    for (int t = 0; t < 4; t++) {
        v[t]      = acc[0][t] + b0[t];
        v[4 + t]  = acc[1][t] + b1[t];
        v[8 + t]  = acc[2][t] + b2[t];
        v[12 + t] = acc[3][t] + b3[t];
    }
    if (NM == 4) {
        if (sig) {
            #pragma unroll
            for (int t = 0; t < 16; t++) v[t] = sigm(v[t]);
        }
        u16 o[16];
        #pragma unroll
        for (int t = 0; t < 16; t++) o[t] = f2b(v[t]);
        u16* Cp = C + (size_t)row * 256;
        *(uint4*)&Cp[base0] = *(uint4*)&o[0];
        *(uint4*)&Cp[base1] = *(uint4*)&o[8];
    } else {
        // fused combine: out = e + v*gate*sigm(aw), fp32
        (void)C; (void)sig;
        const float* X     = f1 ? cfgs.x0 : cfgs.x1;
        const u16* gate    = f1 ? cfgs.gate0 : cfgs.gate1;
        const float* scale = f1 ? cfgs.scale0 : cfgs.scale1;
        const float* pe    = cfgs.pe;
        const float sc = scale[0];
        const int pos  = f1 ? (row % DLn) : (row % PLc);
        const int bidx = f1 ? (row / DLn) : (row / PLc);
        const int orow = bidx * 1290 + (f1 ? pos : 290 + pos);
        float aw[16];
        if (f1) {
            const float* dfc = cfgs.dfc;
            *(float4*)&aw[0]  = *(const float4*)&dfc[base0];
            *(float4*)&aw[4]  = *(const float4*)&dfc[base0 + 4];
            *(float4*)&aw[8]  = *(const float4*)&dfc[base1];
            *(float4*)&aw[12] = *(const float4*)&dfc[base1 + 4];
        } else {
            float cmv[8];
            float4 ca = *(const float4*)&cfgs.cm[(size_t)row * 8];
            float4 cb = *(const float4*)&cfgs.cm[(size_t)row * 8 + 4];
            cmv[0]=ca.x; cmv[1]=ca.y; cmv[2]=ca.z; cmv[3]=ca.w;
            cmv[4]=cb.x; cmv[5]=cb.y; cmv[6]=cb.z; cmv[7]=cb.w;
            #pragma unroll
            for (int t = 0; t < 16; t++) {
                const int col = (t < 8) ? (base0 + t) : (base1 + t - 8);
                float s2 = fcb[2048 + col];
                #pragma unroll
                for (int hh = 0; hh < 8; hh++) s2 += cmv[hh] * fcb[hh * 256 + col];
                aw[t] = s2;
            }
        }
        u16 ge[16];
        *(uint4*)&ge[0] = *(const uint4*)&gate[(size_t)row * 256 + base0];
        *(uint4*)&ge[8] = *(const uint4*)&gate[(size_t)row * 256 + base1];
        float outv[16];
        #pragma unroll
        for (int half = 0; half < 2; half++) {
            const int cb0 = half ? base1 : base0;
            #pragma unroll
            for (int t4 = 0; t4 < 2; t4++) {
                float4 xa = *(const float4*)&X[(size_t)row * 256 + cb0 + t4 * 4];
                float4 pa = *(const float4*)&pe[(size_t)pos * 256 + cb0 + t4 * 4];
                #pragma unroll
                for (int t = 0; t < 4; t++) {
                    const int idx = half * 8 + t4 * 4 + t;
                    float e = (&xa.x)[t] + sc * (&pa.x)[t];
                    outv[idx] = e + v[idx] * b2f(ge[idx]) * sigm(aw[idx]);
                }
            }
        }
        float* Op = cfgs.out + (size_t)orow * 256;
        *(float4*)&Op[base0]     = *(float4*)&outv[0];
        *(float4*)&Op[base0 + 4] = *(float4*)&outv[4];
        *(float4*)&Op[base1]     = *(float4*)&outv[8];
        *(float4*)&Op[base1 + 4] = *(float4*)&outv[12];
    }
}

// ---------------- attention: one block per (b,h), no-max softmax, 2 sweeps ----------------
// Q' scales folded with log2(e): P = 2^S via __builtin_amdgcn_exp2f (bare v_exp_f32).
// P -> bf16 via native __bf16 cast (compiler emits v_cvt_pk_bf16_f32; 1 op vs 4-op bit-math).
__global__ __launch_bounds__(512) void attn_kernel(
        const u16* __restrict__ Qd, const u16* __restrict__ Kd, const u16* __restrict__ Vd,
        const u16* __restrict__ Kp, const u16* __restrict__ Vp, const u16* __restrict__ Qp,
        const float* __restrict__ alpha,
        u16* __restrict__ ctx_d, u16* __restrict__ ctx_p, float* __restrict__ cm) {
    __shared__ u16 Ks[2][64 * 64];
    __shared__ union {
        struct { u16 VpT[2][32 * 64]; u16 Pm[320 * 64]; } s1;
        struct { u16 PT[64 * 320]; u16 VdT[32 * 320]; } s2;
    } U;
    __shared__ float r_l[320];
    __shared__ float colpart[8][64];

    const int bh = blockIdx.x, b = bh >> 3, h = bh & 7;
    const int tid = threadIdx.x;
    const int w = tid >> 6, lane = tid & 63, ln = lane & 15, g = lane >> 4;

    const float a = sigm(alpha[0]);
    const float inv = 0.1767766952966369f;       // 1/sqrt(32)
    const float l2e = 1.4426950408889634f;       // log2(e)
    const float sa = a * inv * l2e, sb = (1.0f - a) * inv * l2e;
    const int nmt = (w < 4) ? 3 : 2;
    const int mtsA[3] = { w, w + 8, w + 16 };

    const size_t rbd = (size_t)b * DLn * 256 + h * 32;
    const size_t rbp = (size_t)b * PLc * 256 + h * 32;

    bf16x8 Qf[3][2];
    #pragma unroll
    for (int t = 0; t < 3; t++) {
        const int i = mtsA[t] * 16 + ln;
        #pragma unroll
        for (int ks = 0; ks < 2; ks++) {
            u16 o[8] = {0,0,0,0,0,0,0,0};
            if (t < nmt && i < DLn) {
                const u16* src = (ks ? Kd : Qd) + rbd + (size_t)i * 256 + g * 8;
                const float s = ks ? sb : sa;
                uint4 v = *(const uint4*)src;
                u16 e[8]; *(uint4*)e = v;
                #pragma unroll
                for (int q = 0; q < 8; q++) o[q] = f2bh(b2f(e[q]) * s);
            }
            Qf[t][ks] = *(bf16x8*)o;
        }
    }

    const int s_jj = tid >> 3, s_ch = tid & 7;
    const u16* s_src = ((s_ch >> 2) ? Qp : Kp) + rbp + (s_ch & 3) * 8;
    const int v_j = tid & 63, v_d0 = (tid >> 6) * 4;

    {
        int j = s_jj;
        uint4 kv = (j < PLc) ? *(const uint4*)(s_src + (size_t)j * 256) : make_uint4(0,0,0,0);
        uint2 vv = (v_j < PLc) ? *(const uint2*)(Vp + rbp + (size_t)v_j * 256 + v_d0) : make_uint2(0,0);
        *(uint4*)&Ks[0][sw(s_jj, s_ch * 8, 64)] = kv;
        u16 e[4]; *(uint2*)e = vv;
        #pragma unroll
        for (int q = 0; q < 4; q++) U.s1.VpT[0][sw(v_d0 + q, v_j, 64)] = e[q];
    }
    __syncthreads();

    float rs[3] = {0.f, 0.f, 0.f};
    f32x4 accd[3][2] = {};
    for (int jt = 0; jt < 16; jt++) {
        const int cur = jt & 1, j0 = jt * 64;
        const int jn = j0 + 64 + s_jj;
        uint4 kv = (jn < PLc) ? *(const uint4*)(s_src + (size_t)jn * 256) : make_uint4(0,0,0,0);
        const int vn = j0 + 64 + v_j;
        uint2 vv = (vn < PLc) ? *(const uint2*)(Vp + rbp + (size_t)vn * 256 + v_d0) : make_uint2(0,0);

        bf16x8 kf[4][2];
        #pragma unroll
        for (int js = 0; js < 4; js++)
            #pragma unroll
            for (int ks = 0; ks < 2; ks++)
                kf[js][ks] = *(const bf16x8*)&Ks[cur][sw(js * 16 + ln, ks * 32 + g * 8, 64)];

        #pragma unroll
        for (int t = 0; t < 3; t++) {
            if (t >= nmt) break;
            const int mt = mtsA[t];
            f32x4 acc[4] = {};
            #pragma unroll
            for (int ks = 0; ks < 2; ks++)
                #pragma unroll
                for (int js = 0; js < 4; js++)
                    acc[js] = __builtin_amdgcn_mfma_f32_16x16x32_bf16(kf[js][ks], Qf[t][ks], acc[js], 0, 0, 0);
            const int irow = mt * 16 + ln;
            #pragma unroll
            for (int js = 0; js < 4; js++) {
                u16 pb[4];
                float psum = 0.f;
                #pragma unroll
                for (int r = 0; r < 4; r++) {
                    float p = fexp2(acc[js][r]);
                    psum += p;
                    pb[r] = f2bh(p);
                }
                rs[t] += psum;
                *(ushort4*)&U.s1.Pm[sw(irow, js * 16 + g * 4, 64)] = *(ushort4*)pb;
            }
        }
        #pragma unroll
        for (int t = 0; t < 3; t++) {
            if (t >= nmt) break;
            const int mt = mtsA[t];
            #pragma unroll
            for (int ks2 = 0; ks2 < 2; ks2++) {
                bf16x8 af = *(const bf16x8*)&U.s1.Pm[sw(mt * 16 + ln, ks2 * 32 + g * 8, 64)];
                #pragma unroll
                for (int nd = 0; nd < 2; nd++) {
                    bf16x8 bv = *(const bf16x8*)&U.s1.VpT[cur][sw(nd * 16 + ln, ks2 * 32 + g * 8, 64)];
                    accd[t][nd] = __builtin_amdgcn_mfma_f32_16x16x32_bf16(bv, af, accd[t][nd], 0, 0, 0);
                }
            }
        }
        *(uint4*)&Ks[cur ^ 1][sw(s_jj, s_ch * 8, 64)] = kv;
        {
            u16 e[4]; *(uint2*)e = vv;
            #pragma unroll
            for (int q = 0; q < 4; q++) U.s1.VpT[cur ^ 1][sw(v_d0 + q, v_j, 64)] = e[q];
        }
        __syncthreads();
    }

    #pragma unroll
    for (int t = 0; t < 3; t++) {
        float v = rs[t];
        v += __shfl_xor(v, 16);
        v += __shfl_xor(v, 32);
        rs[t] = v;
    }
    if (g == 0) {
        #pragma unroll
        for (int t = 0; t < 3; t++) {
            if (t >= nmt) break;
            const int i = mtsA[t] * 16 + ln;
            r_l[i] = (i < DLn) ? 1.0f / (rs[t] - 24.0f) : 0.0f;
        }
    }
    __syncthreads();

    #pragma unroll
    for (int t = 0; t < 3; t++) {
        if (t >= nmt) break;
        const int i = mtsA[t] * 16 + ln;
        if (i < DLn) {
            const float ri = r_l[i];
            #pragma unroll
            for (int nd = 0; nd < 2; nd++) {
                u16 o[4];
                #pragma unroll
                for (int r = 0; r < 4; r++) o[r] = f2bh(accd[t][nd][r] * ri);
                *(uint2*)&ctx_d[rbd + (size_t)i * 256 + nd * 16 + g * 4] = *(uint2*)o;
            }
        }
    }
    for (int c = tid; c < 320 * 8; c += 512) {
        const int i = c >> 3, d0 = (c & 7) * 4;
        u16 o[4] = {0,0,0,0};
        if (i < DLn) {
            const float ri = r_l[i];
            uint2 v = *(const uint2*)(Vd + rbd + (size_t)i * 256 + d0);
            u16 e[4]; *(uint2*)e = v;
            #pragma unroll
            for (int q = 0; q < 4; q++) o[q] = f2bh(b2f(e[q]) * ri);
        }
        #pragma unroll
        for (int q = 0; q < 4; q++) U.s2.VdT[sw(d0 + q, i, 320)] = o[q];
    }
    {
        int j = s_jj;
        uint4 kv = (j < PLc) ? *(const uint4*)(s_src + (size_t)j * 256) : make_uint4(0,0,0,0);
        *(uint4*)&Ks[0][sw(s_jj, s_ch * 8, 64)] = kv;
    }
    float rr[3][4];
    #pragma unroll
    for (int t = 0; t < 3; t++)
        #pragma unroll
        for (int r = 0; r < 4; r++)
            rr[t][r] = (t < nmt) ? r_l[mtsA[t] * 16 + g * 4 + r] : 0.0f;
    __syncthreads();

    for (int jt = 0; jt < 16; jt++) {
        const int cur = jt & 1, j0 = jt * 64;
        const int jn = j0 + 64 + s_jj;
        uint4 kv = (jn < PLc) ? *(const uint4*)(s_src + (size_t)jn * 256) : make_uint4(0,0,0,0);

        bf16x8 kf[4][2];
        #pragma unroll
        for (int js = 0; js < 4; js++)
            #pragma unroll
            for (int ks = 0; ks < 2; ks++)
                kf[js][ks] = *(const bf16x8*)&Ks[cur][sw(js * 16 + ln, ks * 32 + g * 8, 64)];

        float csl[4] = {0.f, 0.f, 0.f, 0.f};
        #pragma unroll
        for (int t = 0; t < 3; t++) {
            if (t >= nmt) break;
            const int mt = mtsA[t];
            f32x4 acc[4] = {};
            #pragma unroll
            for (int ks = 0; ks < 2; ks++)
                #pragma unroll
                for (int js = 0; js < 4; js++)
                    acc[js] = __builtin_amdgcn_mfma_f32_16x16x32_bf16(Qf[t][ks], kf[js][ks], acc[js], 0, 0, 0);
            #pragma unroll
            for (int js = 0; js < 4; js++) {
                u16 pb[4];
                #pragma unroll
                for (int r = 0; r < 4; r++) {
                    float p = fexp2(acc[js][r]);
                    csl[js] += p * rr[t][r];
                    pb[r] = f2bh(p);
                }
                *(ushort4*)&U.s2.PT[sw(js * 16 + ln, mt * 16 + g * 4, 320)] = *(ushort4*)pb;
            }
        }
        #pragma unroll
        for (int js = 0; js < 4; js++) {
            float v = csl[js];
            v += __shfl_xor(v, 16);
            v += __shfl_xor(v, 32);
            csl[js] = v;
        }
        if (g == 0) {
            #pragma unroll
            for (int js = 0; js < 4; js++) colpart[w][js * 16 + ln] = csl[js];
        }
        *(uint4*)&Ks[cur ^ 1][sw(s_jj, s_ch * 8, 64)] = kv;
        __syncthreads();

        {
            const int js2 = w & 3, ds2 = w >> 2;
            f32x4 ap = {};
            #pragma unroll
            for (int k = 0; k < 10; k++) {
                bf16x8 af = *(const bf16x8*)&U.s2.PT[sw(js2 * 16 + ln, k * 32 + g * 8, 320)];
                bf16x8 bv = *(const bf16x8*)&U.s2.VdT[sw(ds2 * 16 + ln, k * 32 + g * 8, 320)];
                ap = __builtin_amdgcn_mfma_f32_16x16x32_bf16(bv, af, ap, 0, 0, 0);
            }
            const int j = j0 + js2 * 16 + ln;
            if (j < PLc) {
                u16 o[4];
                #pragma unroll
                for (int r = 0; r < 4; r++) o[r] = f2bh(ap[r]);
                *(uint2*)&ctx_p[rbp + (size_t)j * 256 + ds2 * 16 + g * 4] = *(uint2*)o;
            }
        }
        if (w == 0) {
            float tot = 0.f;
            #pragma unroll
            for (int ww = 0; ww < 8; ww++) tot += colpart[ww][lane];
            const int j = j0 + lane;
            if (j < PLc) cm[(size_t)(b * PLc + j) * 8 + h] = tot * (1.0f / 290.0f);
        }
        __syncthreads();
    }
}

extern "C" void kernel_launch(void* const* d_in, const int* in_sizes, int n_in,
                              void* d_out, int out_size, void* d_ws, size_t ws_size,
                              hipStream_t stream) {
    (void)in_sizes; (void)n_in; (void)out_size;
    const float* drug    = (const float*)d_in[0];
    const float* prot    = (const float*)d_in[1];
    const float* scale_d = (const float*)d_in[2];
    const float* scale_p = (const float*)d_in[3];

    char* ws = (char*)d_ws;
    size_t off = 0;
    auto alloc = [&](size_t bytes) -> void* {
        void* p = ws + off;
        off += (bytes + 255) & ~(size_t)255;
        return p;
    };
    float* pe   = (float*)alloc((size_t)1000 * 256 * 4);
    u16* wt     = (u16*)alloc((size_t)10 * 65536 * 2);
    u16* e_d    = (u16*)alloc((size_t)MD * 256 * 2);
    u16* e_p    = (u16*)alloc((size_t)MP * 256 * 2);
    u16* Qd     = (u16*)alloc((size_t)MD * 256 * 2);
    u16* Kd     = (u16*)alloc((size_t)MD * 256 * 2);
    u16* Vd     = (u16*)alloc((size_t)MD * 256 * 2);
    u16* gate_d = (u16*)alloc((size_t)MD * 256 * 2);
    u16* Kp     = (u16*)alloc((size_t)MP * 256 * 2);
    u16* Vp     = (u16*)alloc((size_t)MP * 256 * 2);
    u16* Qp     = (u16*)alloc((size_t)MP * 256 * 2);
    u16* gate_p = (u16*)alloc((size_t)MP * 256 * 2);
    u16* ctxd   = (u16*)alloc((size_t)MD * 256 * 2);
    u16* ctxp   = (u16*)alloc((size_t)MP * 256 * 2);
    float* cm   = (float*)alloc((size_t)MP * 8 * 4);
    float* dfc  = (float*)alloc((size_t)256 * 4);
    if (off > ws_size) return;

    pe_kernel<<<1000, 256, 0, stream>>>(pe);
    fcprep_kernel<<<1, 256, 0, stream>>>((const float*)d_in[21], (const float*)d_in[22], dfc);

    WPtrs wp;
    const int wsrc[10] = {4, 12, 14, 25, 6, 8, 10, 27, 16, 18};
    for (int m = 0; m < 10; m++) wp.w[m] = (const float*)d_in[wsrc[m]];
    wprep_kernel<<<dim3(16, 10), 256, 0, stream>>>(wp, wt);

    eadd_kernel<<<(MD + MP) / 4, 256, 0, stream>>>(drug, prot, scale_d, scale_p, pe, e_d, e_p);

    auto W = [&](int slot) { return wt + (size_t)slot * 65536; };

    PCfg2 p1 = {};
    p1.c0 = { e_d,
              { { W(0), (const float*)d_in[5],  Qd,     0 },
                { W(1), (const float*)d_in[13], Kd,     0 },
                { W(2), (const float*)d_in[15], Vd,     0 },
                { W(3), (const float*)d_in[26], gate_d, 1 } } };
    p1.c1 = { e_p,
              { { W(4), (const float*)d_in[7],  Kp,     0 },
                { W(5), (const float*)d_in[9],  Vp,     0 },
                { W(6), (const float*)d_in[11], Qp,     0 },
                { W(7), (const float*)d_in[28], gate_p, 1 } } };
    proj_kernel<4><<<SG * 8 * 16, 256, 0, stream>>>(p1);

    attn_kernel<<<256, 512, 0, stream>>>(Qd, Kd, Vd, Kp, Vp, Qp,
                                         (const float*)d_in[20], ctxd, ctxp, cm);

    PCfg2 p2 = {};
    p2.c0 = { ctxd, { { W(8), (const float*)d_in[17], nullptr, 0 }, {}, {}, {} } };
    p2.c1 = { ctxp, { { W(9), (const float*)d_in[19], nullptr, 0 }, {}, {}, {} } };
    p2.x0 = drug;  p2.x1 = prot;
    p2.gate0 = gate_d;  p2.gate1 = gate_p;
    p2.cm = cm;
    p2.dfc = dfc;
    p2.wfc1 = (const float*)d_in[23];  p2.bfc1 = (const float*)d_in[24];
    p2.scale0 = scale_d;  p2.scale1 = scale_p;
    p2.pe = pe;
    p2.out = (float*)d_out;
    proj_kernel<1><<<SG * 8 * 4, 256, 0, stream>>>(p2);
}